// Round 5
// baseline (354.616 us; speedup 1.0000x reference)
//
#include <hip/hip_runtime.h>
#include <math.h>

// Problem constants
#define DIMC 256   // input channels
#define NCH  176   // 128 q + 16 k + 32 v output channels
#define MM   1024  // N2 spatial
#define BB   16    // batch
#define KD   16    // DIM_K
#define HH   8     // heads
#define VD   32    // DIM_V
#define EPSV 1e-5
#define OPAD 192   // padded output channels for MFMA proj (12 o-tiles)

typedef short short8 __attribute__((ext_vector_type(8)));
typedef float f32x4  __attribute__((ext_vector_type(4)));
typedef unsigned u32x4v __attribute__((ext_vector_type(4)));
typedef u32x4v u32x4a __attribute__((aligned(4)));   // 4-byte-aligned dwordx4

union frag8 { unsigned u[4]; short8 s; u32x4v v; };

__device__ __forceinline__ unsigned bf16rne(float f) {
    unsigned u = __float_as_uint(f);
    unsigned r = u + 0x7FFFu + ((u >> 16) & 1u);
    return r >> 16;
}
__device__ __forceinline__ float bf16tof(unsigned h) {
    return __uint_as_float(h << 16);
}

#define GL2LDS16(g, l) __builtin_amdgcn_global_load_lds( \
    (const __attribute__((address_space(1))) unsigned*)(g), \
    (__attribute__((address_space(3))) unsigned*)(l), 16, 0, 0)

// ---------------------------------------------------------------------------
// k_wprep: pack W (q|k|v concat, padded to 192 rows) into 4 planes of
// [192][128] u32, each u32 = bf16(c odd)<<16 | bf16(c even):
//   plane 0 = re_hi, 1 = im_hi, 2 = re_lo, 3 = im_lo  (hi/lo split-bf16)
// ---------------------------------------------------------------------------
__global__ __launch_bounds__(256) void k_wprep(
    const float* __restrict__ wq_re, const float* __restrict__ wq_im,
    const float* __restrict__ wk_re, const float* __restrict__ wk_im,
    const float* __restrict__ wv_re, const float* __restrict__ wv_im,
    unsigned* __restrict__ Wpk)
{
    int idx = blockIdx.x * 256 + threadIdx.x;   // 0..24575
    if (idx >= OPAD * 128) return;
    int o = idx >> 7, j = idx & 127;
    int c0 = 2 * j;
    float r0 = 0.f, r1 = 0.f, i0 = 0.f, i1 = 0.f;
    if (o < 128) {
        r0 = wq_re[o * DIMC + c0]; r1 = wq_re[o * DIMC + c0 + 1];
        i0 = wq_im[o * DIMC + c0]; i1 = wq_im[o * DIMC + c0 + 1];
    } else if (o < 144) {
        int oo = o - 128;
        r0 = wk_re[oo * DIMC + c0]; r1 = wk_re[oo * DIMC + c0 + 1];
        i0 = wk_im[oo * DIMC + c0]; i1 = wk_im[oo * DIMC + c0 + 1];
    } else if (o < 176) {
        int oo = o - 144;
        r0 = wv_re[oo * DIMC + c0]; r1 = wv_re[oo * DIMC + c0 + 1];
        i0 = wv_im[oo * DIMC + c0]; i1 = wv_im[oo * DIMC + c0 + 1];
    }
    unsigned rh0 = bf16rne(r0), rh1 = bf16rne(r1);
    unsigned ih0 = bf16rne(i0), ih1 = bf16rne(i1);
    float rl0 = r0 - bf16tof(rh0), rl1 = r1 - bf16tof(rh1);
    float il0 = i0 - bf16tof(ih0), il1 = i1 - bf16tof(ih1);
    Wpk[0 * OPAD * 128 + idx] = rh0 | (rh1 << 16);
    Wpk[1 * OPAD * 128 + idx] = ih0 | (ih1 << 16);
    Wpk[2 * OPAD * 128 + idx] = bf16rne(rl0) | (bf16rne(rl1) << 16);
    Wpk[3 * OPAD * 128 + idx] = bf16rne(il0) | (bf16rne(il1) << 16);
}

// ---------------------------------------------------------------------------
// k_proj (MFMA): O[b][o][m] = sum_c W[o][c]*X[b][c][m], complex, split-bf16
// (3-term: hi*hi + hi*lo + lo*hi) => ~fp32 accuracy.  (unchanged from R4)
// ---------------------------------------------------------------------------
__global__ __launch_bounds__(256, 2) void k_proj(
    const float* __restrict__ x_re, const float* __restrict__ x_im,
    const unsigned* __restrict__ Wpk,
    float2* __restrict__ O)
{
    const int m0  = blockIdx.x * 32;
    const int b   = blockIdx.y;
    const int tid = threadIdx.x;
    const int w    = tid >> 6;
    const int lane = tid & 63;
    const int quad = lane >> 4;
    const int col  = lane & 15;
    const int mt = w & 1, og = w >> 1;

    __shared__ __align__(16) unsigned Wsh[4 * OPAD * 16];  // 48 KB
    __shared__ __align__(16) unsigned Xsh[4 * 32 * 20];    // 10 KB

    f32x4 accR[6], accI[6];
#pragma unroll
    for (int t = 0; t < 6; ++t) {
        accR[t] = (f32x4){0.f, 0.f, 0.f, 0.f};
        accI[t] = (f32x4){0.f, 0.f, 0.f, 0.f};
    }

    const int ms = tid & 31;
    const int cps = tid >> 5;

    for (int kk = 0; kk < 8; ++kk) {
#pragma unroll
        for (int p = 0; p < 12; ++p) {
            int idx = p * 256 + tid;
            int plane = idx / 768;
            int rem = idx - plane * 768;
            int row = rem >> 2, seg = rem & 3;
            u32x4v d = *(const u32x4v*)&Wpk[(size_t)plane * (OPAD * 128) + row * 128 + kk * 16 + seg * 4];
            *(u32x4v*)&Wsh[(plane * OPAD + row) * 16 + seg * 4] = d;
        }
#pragma unroll
        for (int p = 0; p < 2; ++p) {
            int cp = cps + p * 8;
            int c  = kk * 32 + cp * 2;
            size_t base = ((size_t)(b * DIMC + c)) * MM + m0 + ms;
            float r0 = x_re[base],      i0 = x_im[base];
            float r1 = x_re[base + MM], i1 = x_im[base + MM];
            unsigned rh0 = bf16rne(r0), rh1 = bf16rne(r1);
            unsigned ih0 = bf16rne(i0), ih1 = bf16rne(i1);
            float rl0 = r0 - bf16tof(rh0), rl1 = r1 - bf16tof(rh1);
            float il0 = i0 - bf16tof(ih0), il1 = i1 - bf16tof(ih1);
            Xsh[0 * 640 + ms * 20 + cp] = rh0 | (rh1 << 16);
            Xsh[1 * 640 + ms * 20 + cp] = ih0 | (ih1 << 16);
            Xsh[2 * 640 + ms * 20 + cp] = bf16rne(rl0) | (bf16rne(rl1) << 16);
            Xsh[3 * 640 + ms * 20 + cp] = bf16rne(il0) | (bf16rne(il1) << 16);
        }
        __syncthreads();

        int mrow = mt * 16 + col;
        short8 Xrh = *(const short8*)&Xsh[0 * 640 + mrow * 20 + quad * 4];
        short8 Xih = *(const short8*)&Xsh[1 * 640 + mrow * 20 + quad * 4];
        short8 Xrl = *(const short8*)&Xsh[2 * 640 + mrow * 20 + quad * 4];
        short8 Xil = *(const short8*)&Xsh[3 * 640 + mrow * 20 + quad * 4];

#pragma unroll
        for (int ot = 0; ot < 6; ++ot) {
            int orow = (og * 6 + ot) * 16 + col;
            frag8 Arh, Aih, Arl, Ail, Anh, Anl;
            Arh.s = *(const short8*)&Wsh[(0 * OPAD + orow) * 16 + quad * 4];
            Aih.s = *(const short8*)&Wsh[(1 * OPAD + orow) * 16 + quad * 4];
            Arl.s = *(const short8*)&Wsh[(2 * OPAD + orow) * 16 + quad * 4];
            Ail.s = *(const short8*)&Wsh[(3 * OPAD + orow) * 16 + quad * 4];
#pragma unroll
            for (int i = 0; i < 4; ++i) {
                Anh.u[i] = Aih.u[i] ^ 0x80008000u;
                Anl.u[i] = Ail.u[i] ^ 0x80008000u;
            }
            accR[ot] = __builtin_amdgcn_mfma_f32_16x16x32_bf16(Arh.s, Xrh, accR[ot], 0, 0, 0);
            accR[ot] = __builtin_amdgcn_mfma_f32_16x16x32_bf16(Anh.s, Xih, accR[ot], 0, 0, 0);
            accR[ot] = __builtin_amdgcn_mfma_f32_16x16x32_bf16(Arh.s, Xrl, accR[ot], 0, 0, 0);
            accR[ot] = __builtin_amdgcn_mfma_f32_16x16x32_bf16(Anh.s, Xil, accR[ot], 0, 0, 0);
            accR[ot] = __builtin_amdgcn_mfma_f32_16x16x32_bf16(Arl.s, Xrh, accR[ot], 0, 0, 0);
            accR[ot] = __builtin_amdgcn_mfma_f32_16x16x32_bf16(Anl.s, Xih, accR[ot], 0, 0, 0);
            accI[ot] = __builtin_amdgcn_mfma_f32_16x16x32_bf16(Arh.s, Xih, accI[ot], 0, 0, 0);
            accI[ot] = __builtin_amdgcn_mfma_f32_16x16x32_bf16(Aih.s, Xrh, accI[ot], 0, 0, 0);
            accI[ot] = __builtin_amdgcn_mfma_f32_16x16x32_bf16(Arh.s, Xil, accI[ot], 0, 0, 0);
            accI[ot] = __builtin_amdgcn_mfma_f32_16x16x32_bf16(Aih.s, Xrl, accI[ot], 0, 0, 0);
            accI[ot] = __builtin_amdgcn_mfma_f32_16x16x32_bf16(Arl.s, Xih, accI[ot], 0, 0, 0);
            accI[ot] = __builtin_amdgcn_mfma_f32_16x16x32_bf16(Ail.s, Xrh, accI[ot], 0, 0, 0);
        }
        __syncthreads();
    }

#pragma unroll
    for (int ot = 0; ot < 6; ++ot) {
        int gto = og * 6 + ot;
        if (gto >= 11) continue;
#pragma unroll
        for (int r = 0; r < 4; ++r) {
            int o = gto * 16 + quad * 4 + r;
            O[((size_t)(b * NCH + o)) * MM + m0 + mt * 16 + col] =
                make_float2(accR[ot][r], accI[ot][r]);
        }
    }
}

// ---------------------------------------------------------------------------
// K2: complex BN stats (double accumulation), folds to affine A,B  (unchanged)
// ---------------------------------------------------------------------------
__global__ __launch_bounds__(256) void k_bnstats(
    const float2* __restrict__ O,
    const float* __restrict__ qs_re, const float* __restrict__ qs_im,
    const float* __restrict__ qb_re, const float* __restrict__ qb_im,
    const float* __restrict__ vs_re, const float* __restrict__ vs_im,
    const float* __restrict__ vb_re, const float* __restrict__ vb_im,
    float4* __restrict__ stats)
{
    const int ch  = blockIdx.x;
    const int o   = (ch < 128) ? ch : (144 + ch - 128);
    const int tid = threadIdx.x;

    double sr = 0, si = 0, sq = 0, sri = 0;
    for (int idx = tid; idx < BB * MM; idx += 256) {
        int b = idx >> 10, m = idx & 1023;
        float2 val = O[((size_t)(b * NCH + o)) * MM + m];
        double r = val.x, ii = val.y;
        sr += r; si += ii; sq += r * r - ii * ii; sri += r * ii;
    }
    __shared__ double red[4][256];
    red[0][tid] = sr; red[1][tid] = si; red[2][tid] = sq; red[3][tid] = sri;
    __syncthreads();
    for (int s = 128; s > 0; s >>= 1) {
        if (tid < s) {
            red[0][tid] += red[0][tid + s]; red[1][tid] += red[1][tid + s];
            red[2][tid] += red[2][tid + s]; red[3][tid] += red[3][tid + s];
        }
        __syncthreads();
    }
    if (tid == 0) {
        const double inv = 1.0 / (double)(BB * MM);
        double mr = red[0][0] * inv, mi = red[1][0] * inv;
        double vr = red[2][0] * inv - (mr * mr - mi * mi) + EPSV;
        double vi = 2.0 * (red[3][0] * inv - mr * mi);
        double rad = sqrt(vr * vr + vi * vi);
        double wr  = sqrt(fmax(0.5 * (rad + vr), 0.0));
        double wi  = sqrt(fmax(0.5 * (rad - vr), 0.0));
        if (vi < 0) wi = -wi;
        double den = wr * wr + wi * wi;
        double ivr = wr / den, ivi = -wi / den;
        double scr, sci, shr, shi;
        if (ch < 128) { scr = qs_re[ch]; sci = qs_im[ch]; shr = qb_re[ch]; shi = qb_im[ch]; }
        else { int i2 = ch - 128; scr = vs_re[i2]; sci = vs_im[i2]; shr = vb_re[i2]; shi = vb_im[i2]; }
        double Ar = scr * ivr - sci * ivi;
        double Ai = scr * ivi + sci * ivr;
        double Br = shr - (Ar * mr - Ai * mi);
        double Bi = shi - (Ar * mi + Ai * mr);
        stats[ch] = make_float4((float)Ar, (float)Ai, (float)Br, (float)Bi);
    }
}

// ---------------------------------------------------------------------------
// K3a: apply BN affine in place; v channels also emit bf16 planes (unchanged)
// ---------------------------------------------------------------------------
__global__ __launch_bounds__(256) void k_bnapply(
    const float4* __restrict__ stats, float2* __restrict__ O,
    unsigned* __restrict__ VR, unsigned* __restrict__ VI)
{
    int ch = blockIdx.x, b = blockIdx.y;
    int o  = (ch < 128) ? ch : (144 + ch - 128);
    float4 s = stats[ch];
    float2* row = O + ((size_t)(b * NCH + o)) * MM;
    int tid = threadIdx.x;
    for (int mm = tid; mm < 512; mm += 256) {
        float4 two = *(float4*)&row[2 * mm];
        float nr0 = s.x * two.x - s.y * two.y + s.z;
        float ni0 = s.x * two.y + s.y * two.x + s.w;
        float nr1 = s.x * two.z - s.y * two.w + s.z;
        float ni1 = s.x * two.w + s.y * two.z + s.w;
        *(float4*)&row[2 * mm] = make_float4(nr0, ni0, nr1, ni1);
        if (ch >= 128) {
            int bv = b * VD + (ch - 128);
            VR[(size_t)bv * 512 + mm] = bf16rne(nr0) | (bf16rne(nr1) << 16);
            VI[(size_t)bv * 512 + mm] = bf16rne(ni0) | (bf16rne(ni1) << 16);
        }
    }
}

// ---------------------------------------------------------------------------
// k_softlam: softmax over m of |k| fused with content lambda  (unchanged)
// ---------------------------------------------------------------------------
__global__ __launch_bounds__(256) void k_softlam(
    const float2* __restrict__ O, float2* __restrict__ lamc)
{
    int kc = blockIdx.x, b = blockIdx.y;
    const float2* row = O + ((size_t)(b * NCH + 128 + kc)) * MM;
    int tid = threadIdx.x;
    __shared__ float red[256];
    __shared__ float skl[1024];

    float mag[4]; float mx = -1e30f;
#pragma unroll
    for (int j = 0; j < 4; ++j) {
        float2 v = row[tid + j * 256];
        mag[j] = sqrtf(v.x * v.x + v.y * v.y);
        mx = fmaxf(mx, mag[j]);
    }
    red[tid] = mx; __syncthreads();
    for (int s = 128; s > 0; s >>= 1) { if (tid < s) red[tid] = fmaxf(red[tid], red[tid + s]); __syncthreads(); }
    mx = red[0]; __syncthreads();
    float e[4]; float sum = 0.f;
#pragma unroll
    for (int j = 0; j < 4; ++j) { e[j] = expf(mag[j] - mx); sum += e[j]; }
    red[tid] = sum; __syncthreads();
    for (int s = 128; s > 0; s >>= 1) { if (tid < s) red[tid] += red[tid + s]; __syncthreads(); }
    float inv = 1.f / red[0];
#pragma unroll
    for (int j = 0; j < 4; ++j) skl[tid + j * 256] = e[j] * inv;
    __syncthreads();

    int v = tid >> 3, s8 = tid & 7;
    const float2* vrow = O + ((size_t)(b * NCH + 144 + v)) * MM;
    float ar = 0.f, ai = 0.f;
    for (int i = 0; i < 128; ++i) {
        int m = s8 * 128 + i;
        float wgt = skl[m]; float2 vv = vrow[m];
        ar += wgt * vv.x; ai += wgt * vv.y;
    }
    __shared__ float2 part[32][8];
    part[v][s8] = make_float2(ar, ai);
    __syncthreads();
    if (tid < 32) {
        float2 t = part[tid][0];
#pragma unroll
        for (int j = 1; j < 8; ++j) { t.x += part[tid][j].x; t.y += part[tid][j].y; }
        lamc[((size_t)(b * KD + kc)) * VD + tid] = t;
    }
}

// ---------------------------------------------------------------------------
// k_eprep — repack emb into embC[k][di][dj] = u32( bf16(im)<<16 | bf16(re) )
// ---------------------------------------------------------------------------
__global__ __launch_bounds__(256) void k_eprep(
    const float* __restrict__ er, const float* __restrict__ ei,
    unsigned* __restrict__ embC)
{
    int i = blockIdx.x * 256 + threadIdx.x;
    if (i >= 63 * 63 * 16) return;
    int kk = i & 15;
    int rest = i >> 4;
    int dj = rest % 63;
    int di = rest / 63;
    embC[(kk * 63 + di) * 63 + dj] = bf16rne(er[i]) | (bf16rne(ei[i]) << 16);
}

// ---------------------------------------------------------------------------
// k_main (R5): bf16 MFMA for lam_p + fused epilogue.
// R5 change: per-block bv extent halved (128 bv = 4 batches; grid y = 4).
// Per-thread acc tile 128 -> 64 floats, B-frags 32 -> 16 regs — the R4
// version exceeded the (256,2) unified VGPR budget and spilled ~5 f32x4 per
// chunk to scratch (363 MB WRITE_SIZE, memory-bound at 2.3 TB/s).
// A-gather amortization over 4 n is preserved.
// ---------------------------------------------------------------------------
__global__ __launch_bounds__(256, 2) void k_main(
    const float2* __restrict__ O,
    const unsigned* __restrict__ embC,
    const unsigned* __restrict__ VbfR,
    const unsigned* __restrict__ VbfI,
    const float2* __restrict__ lamc,
    float* __restrict__ out, int cplx)
{
    const int tid  = threadIdx.x;
    const int w    = tid >> 6;
    const int lane = tid & 63;
    const int quad = lane >> 4;
    const int col  = lane & 15;

    const int n0  = blockIdx.x * 4;
    const int bvq = blockIdx.y;        // 0..3, 128 bv rows each
    const int b0  = bvq * 4;
    const int ni  = n0 >> 5;
    const int nj0 = n0 & 31;

    __shared__ __align__(16) unsigned shraw[4096];   // V stage 16 KB / lamt
    unsigned* vsR = shraw;                            // [128][16]
    unsigned* vsI = shraw + 2048;
    float2*   lamt = (float2*)shraw;                  // [16k][128bv]
    __shared__ __align__(16) float2 qsh[2048];        // [bl(4)][ch(128)][g(4)]

    // stage q tile (BN already applied in place)
#pragma unroll
    for (int it = 0; it < 8; ++it) {
        int idx = it * 256 + tid;
        int g = idx & 3, ch = (idx >> 2) & 127, bl = idx >> 9;
        qsh[idx] = O[((size_t)((b0 + bl) * NCH + ch)) * MM + n0 + g];
    }

    f32x4 accr[4][2], acci[4][2];
#pragma unroll
    for (int g = 0; g < 4; ++g)
#pragma unroll
        for (int t = 0; t < 2; ++t) {
            accr[g][t] = (f32x4){0.f, 0.f, 0.f, 0.f};
            acci[g][t] = (f32x4){0.f, 0.f, 0.f, 0.f};
        }

    const unsigned* vsrcR = VbfR + (size_t)(bvq * 128) * 512;
    const unsigned* vsrcI = VbfI + (size_t)(bvq * 128) * 512;
    const int rowLane = lane >> 2;
    const int moff    = (lane & 3) * 4;

    for (int c = 0; c < 32; ++c) {
        // ---- stage V chunk: wave w stages rows [w*32, w*32+32), both planes
        {
            const unsigned* gR = vsrcR + ((size_t)(w * 32 + rowLane)) * 512 + c * 16 + moff;
            const unsigned* gI = vsrcI + ((size_t)(w * 32 + rowLane)) * 512 + c * 16 + moff;
#pragma unroll
            for (int r16 = 0; r16 < 2; ++r16) {
                GL2LDS16(gR + (size_t)r16 * 16 * 512, vsR + w * 512 + r16 * 256);
                GL2LDS16(gI + (size_t)r16 * 16 * 512, vsI + w * 512 + r16 * 256);
            }
        }
        __syncthreads();

        // ---- B-fragments (reused across 4 n)
        short8 Br[2], Bi[2];
#pragma unroll
        for (int t = 0; t < 2; ++t) {
            int rowb = w * 32 + t * 16 + col;
            Br[t] = *(const short8*)&vsR[rowb * 16 + quad * 4];
            Bi[t] = *(const short8*)&vsI[rowb * 16 + quad * 4];
        }

        const int di = c - ni + 31;
#pragma unroll
        for (int g = 0; g < 4; ++g) {
            int dj0 = quad * 8 + 31 - (nj0 + g);
            const unsigned* ap = embC + ((size_t)(col * 63 + di)) * 63 + dj0;
            u32x4a d0 = *(const u32x4a*)ap;
            u32x4a d1 = *(const u32x4a*)(ap + 4);
            union { unsigned u[4]; short8 s; } Rr, Ri, Rin;
            Rr.u[0] = __builtin_amdgcn_perm(d0.y, d0.x, 0x05040100u);
            Rr.u[1] = __builtin_amdgcn_perm(d0.w, d0.z, 0x05040100u);
            Rr.u[2] = __builtin_amdgcn_perm(d1.y, d1.x, 0x05040100u);
            Rr.u[3] = __builtin_amdgcn_perm(d1.w, d1.z, 0x05040100u);
            Ri.u[0] = __builtin_amdgcn_perm(d0.y, d0.x, 0x07060302u);
            Ri.u[1] = __builtin_amdgcn_perm(d0.w, d0.z, 0x07060302u);
            Ri.u[2] = __builtin_amdgcn_perm(d1.y, d1.x, 0x07060302u);
            Ri.u[3] = __builtin_amdgcn_perm(d1.w, d1.z, 0x07060302u);
            Rin.u[0] = Ri.u[0] ^ 0x80008000u;
            Rin.u[1] = Ri.u[1] ^ 0x80008000u;
            Rin.u[2] = Ri.u[2] ^ 0x80008000u;
            Rin.u[3] = Ri.u[3] ^ 0x80008000u;
#pragma unroll
            for (int t = 0; t < 2; ++t) {
                accr[g][t] = __builtin_amdgcn_mfma_f32_16x16x32_bf16(Rr.s,  Br[t], accr[g][t], 0, 0, 0);
                accr[g][t] = __builtin_amdgcn_mfma_f32_16x16x32_bf16(Rin.s, Bi[t], accr[g][t], 0, 0, 0);
                acci[g][t] = __builtin_amdgcn_mfma_f32_16x16x32_bf16(Rr.s,  Bi[t], acci[g][t], 0, 0, 0);
                acci[g][t] = __builtin_amdgcn_mfma_f32_16x16x32_bf16(Ri.s,  Br[t], acci[g][t], 0, 0, 0);
            }
        }
        __syncthreads();
    }

    // ---- hoist lam_c (g-invariant)
    float2 lcv[2][4];
#pragma unroll
    for (int t = 0; t < 2; ++t) {
        int bvl = w * 32 + t * 16 + col;
        int bloc = b0 + (bvl >> 5), v = bvl & 31;
#pragma unroll
        for (int r = 0; r < 4; ++r)
            lcv[t][r] = lamc[((size_t)(bloc * KD + quad * 4 + r)) * VD + v];
    }

    // ---- epilogue (fully unrolled; g compile-time)
    const int col128 = tid & 127;
    const int hb = (tid >> 7) * 4;          // 4 heads per thread-half
    const int bl = col128 >> 5, vY = col128 & 31;
    const int bY = b0 + bl;
    float2* op2 = (float2*)out;
#pragma unroll
    for (int g = 0; g < 4; ++g) {
        __syncthreads();
#pragma unroll
        for (int t = 0; t < 2; ++t) {
            int bvl = w * 32 + t * 16 + col;
#pragma unroll
            for (int r = 0; r < 4; ++r) {
                int k = quad * 4 + r;
                lamt[k * 128 + bvl] = make_float2(accr[g][t][r] + lcv[t][r].x,
                                                  acci[g][t][r] + lcv[t][r].y);
            }
        }
        __syncthreads();
        float yr[4], yi[4];
#pragma unroll
        for (int h = 0; h < 4; ++h) { yr[h] = 0.f; yi[h] = 0.f; }
#pragma unroll
        for (int k = 0; k < 16; ++k) {
            float2 l = lamt[k * 128 + col128];
#pragma unroll
            for (int h = 0; h < 4; ++h) {
                float2 q = qsh[(bl * 128 + (hb + h) * 16 + k) * 4 + g];
                yr[h] += q.x * l.x - q.y * l.y;
                yi[h] += q.x * l.y + q.y * l.x;
            }
        }
        int n = n0 + g;
        if (cplx) {
#pragma unroll
            for (int h = 0; h < 4; ++h)
                op2[((size_t)(bY * 256 + (hb + h) * 32 + vY)) * MM + n] = make_float2(yr[h], yi[h]);
        } else {
#pragma unroll
            for (int h = 0; h < 4; ++h)
                out[((size_t)(bY * 256 + (hb + h) * 32 + vY)) * MM + n] = yr[h];
        }
    }
}

// ---------------------------------------------------------------------------
extern "C" void kernel_launch(void* const* d_in, const int* in_sizes, int n_in,
                              void* d_out, int out_size, void* d_ws, size_t ws_size,
                              hipStream_t stream)
{
    const float* x_re  = (const float*)d_in[0];
    const float* x_im  = (const float*)d_in[1];
    const float* wq_re = (const float*)d_in[2];
    const float* wq_im = (const float*)d_in[3];
    const float* wk_re = (const float*)d_in[4];
    const float* wk_im = (const float*)d_in[5];
    const float* wv_re = (const float*)d_in[6];
    const float* wv_im = (const float*)d_in[7];
    const float* qs_re = (const float*)d_in[8];
    const float* qs_im = (const float*)d_in[9];
    const float* qb_re = (const float*)d_in[10];
    const float* qb_im = (const float*)d_in[11];
    const float* vs_re = (const float*)d_in[12];
    const float* vs_im = (const float*)d_in[13];
    const float* vb_re = (const float*)d_in[14];
    const float* vb_im = (const float*)d_in[15];
    const float* emb_re = (const float*)d_in[16];
    const float* emb_im = (const float*)d_in[17];

    float* ws = (float*)d_ws;
    const size_t O_OFF  = 0;                                     // 5,767,168
    const size_t ST_OFF = O_OFF + (size_t)BB * NCH * MM * 2;     // 640
    const size_t LC_OFF = ST_OFF + 640;                          // 16,384
    const size_t EC_OFF = LC_OFF + 16384;                        // 63,504
    const size_t WP_OFF = EC_OFF + 63504;                        // 98,304 (Wpk)
    const size_t VR_OFF = WP_OFF + 98304;                        // 262,144
    const size_t VI_OFF = VR_OFF + 262144;                       // 262,144

    float2*   O     = (float2*)(ws + O_OFF);
    float4*   stats = (float4*)(ws + ST_OFF);
    float2*   lamc  = (float2*)(ws + LC_OFF);
    unsigned* embC  = (unsigned*)(ws + EC_OFF);
    unsigned* Wpk   = (unsigned*)(ws + WP_OFF);
    unsigned* VbfR  = (unsigned*)(ws + VR_OFF);
    unsigned* VbfI  = (unsigned*)(ws + VI_OFF);
    float*    outp  = (float*)d_out;

    int cplx = (out_size >= 2 * BB * 256 * MM) ? 1 : 0;

    k_wprep<<<dim3(96), 256, 0, stream>>>(wq_re, wq_im, wk_re, wk_im,
                                          wv_re, wv_im, Wpk);
    k_eprep<<<dim3(249), 256, 0, stream>>>(emb_re, emb_im, embC);
    k_proj<<<dim3(32, BB), 256, 0, stream>>>(x_re, x_im, Wpk, O);
    k_bnstats<<<dim3(160), 256, 0, stream>>>(O, qs_re, qs_im, qb_re, qb_im,
                                             vs_re, vs_im, vb_re, vb_im, stats);
    k_bnapply<<<dim3(160, BB), 256, 0, stream>>>(stats, O, VbfR, VbfI);
    k_softlam<<<dim3(KD, BB), 256, 0, stream>>>(O, lamc);
    k_main<<<dim3(256, 4), 256, 0, stream>>>(O, embC, VbfR, VbfI, lamc, outp, cplx);
}

// Round 6
// 330.004 us; speedup vs baseline: 1.0746x; 1.0746x over previous
//
#include <hip/hip_runtime.h>
#include <math.h>

// Problem constants
#define DIMC 256   // input channels
#define NCH  176   // 128 q + 16 k + 32 v output channels
#define MM   1024  // N2 spatial
#define BB   16    // batch
#define KD   16    // DIM_K
#define HH   8     // heads
#define VD   32    // DIM_V
#define EPSV 1e-5
#define OPAD 192   // padded output channels for MFMA proj (12 o-tiles)

typedef short short8 __attribute__((ext_vector_type(8)));
typedef float f32x4  __attribute__((ext_vector_type(4)));
typedef unsigned u32x4v __attribute__((ext_vector_type(4)));
typedef u32x4v u32x4a __attribute__((aligned(4)));   // 4-byte-aligned dwordx4

union frag8 { unsigned u[4]; short8 s; u32x4v v; };

__device__ __forceinline__ unsigned bf16rne(float f) {
    unsigned u = __float_as_uint(f);
    unsigned r = u + 0x7FFFu + ((u >> 16) & 1u);
    return r >> 16;
}
__device__ __forceinline__ float bf16tof(unsigned h) {
    return __uint_as_float(h << 16);
}

#define GL2LDS16(g, l) __builtin_amdgcn_global_load_lds( \
    (const __attribute__((address_space(1))) unsigned*)(g), \
    (__attribute__((address_space(3))) unsigned*)(l), 16, 0, 0)

// ---------------------------------------------------------------------------
// k_wprep: pack W (q|k|v concat, padded to 192 rows) into 4 planes of
// [192][128] u32 (re_hi / im_hi / re_lo / im_lo, split-bf16).  (unchanged)
// ---------------------------------------------------------------------------
__global__ __launch_bounds__(256) void k_wprep(
    const float* __restrict__ wq_re, const float* __restrict__ wq_im,
    const float* __restrict__ wk_re, const float* __restrict__ wk_im,
    const float* __restrict__ wv_re, const float* __restrict__ wv_im,
    unsigned* __restrict__ Wpk)
{
    int idx = blockIdx.x * 256 + threadIdx.x;   // 0..24575
    if (idx >= OPAD * 128) return;
    int o = idx >> 7, j = idx & 127;
    int c0 = 2 * j;
    float r0 = 0.f, r1 = 0.f, i0 = 0.f, i1 = 0.f;
    if (o < 128) {
        r0 = wq_re[o * DIMC + c0]; r1 = wq_re[o * DIMC + c0 + 1];
        i0 = wq_im[o * DIMC + c0]; i1 = wq_im[o * DIMC + c0 + 1];
    } else if (o < 144) {
        int oo = o - 128;
        r0 = wk_re[oo * DIMC + c0]; r1 = wk_re[oo * DIMC + c0 + 1];
        i0 = wk_im[oo * DIMC + c0]; i1 = wk_im[oo * DIMC + c0 + 1];
    } else if (o < 176) {
        int oo = o - 144;
        r0 = wv_re[oo * DIMC + c0]; r1 = wv_re[oo * DIMC + c0 + 1];
        i0 = wv_im[oo * DIMC + c0]; i1 = wv_im[oo * DIMC + c0 + 1];
    }
    unsigned rh0 = bf16rne(r0), rh1 = bf16rne(r1);
    unsigned ih0 = bf16rne(i0), ih1 = bf16rne(i1);
    float rl0 = r0 - bf16tof(rh0), rl1 = r1 - bf16tof(rh1);
    float il0 = i0 - bf16tof(ih0), il1 = i1 - bf16tof(ih1);
    Wpk[0 * OPAD * 128 + idx] = rh0 | (rh1 << 16);
    Wpk[1 * OPAD * 128 + idx] = ih0 | (ih1 << 16);
    Wpk[2 * OPAD * 128 + idx] = bf16rne(rl0) | (bf16rne(rl1) << 16);
    Wpk[3 * OPAD * 128 + idx] = bf16rne(il0) | (bf16rne(il1) << 16);
}

// ---------------------------------------------------------------------------
// k_proj (MFMA, split-bf16). R6: kk-loop NOT unrolled (#pragma unroll 1) —
// the fully-unrolled 8x ~300-instr body overflowed the 32 KB I$.
// ---------------------------------------------------------------------------
__global__ __launch_bounds__(256, 2) void k_proj(
    const float* __restrict__ x_re, const float* __restrict__ x_im,
    const unsigned* __restrict__ Wpk,
    float2* __restrict__ O)
{
    const int m0  = blockIdx.x * 32;
    const int b   = blockIdx.y;
    const int tid = threadIdx.x;
    const int w    = tid >> 6;
    const int lane = tid & 63;
    const int quad = lane >> 4;
    const int col  = lane & 15;
    const int mt = w & 1, og = w >> 1;

    __shared__ __align__(16) unsigned Wsh[4 * OPAD * 16];  // 48 KB
    __shared__ __align__(16) unsigned Xsh[4 * 32 * 20];    // 10 KB

    f32x4 accR[6], accI[6];
#pragma unroll
    for (int t = 0; t < 6; ++t) {
        accR[t] = (f32x4){0.f, 0.f, 0.f, 0.f};
        accI[t] = (f32x4){0.f, 0.f, 0.f, 0.f};
    }

    const int ms = tid & 31;
    const int cps = tid >> 5;

#pragma unroll 1
    for (int kk = 0; kk < 8; ++kk) {
#pragma unroll
        for (int p = 0; p < 12; ++p) {
            int idx = p * 256 + tid;
            int plane = idx / 768;
            int rem = idx - plane * 768;
            int row = rem >> 2, seg = rem & 3;
            u32x4v d = *(const u32x4v*)&Wpk[(size_t)plane * (OPAD * 128) + row * 128 + kk * 16 + seg * 4];
            *(u32x4v*)&Wsh[(plane * OPAD + row) * 16 + seg * 4] = d;
        }
#pragma unroll
        for (int p = 0; p < 2; ++p) {
            int cp = cps + p * 8;
            int c  = kk * 32 + cp * 2;
            size_t base = ((size_t)(b * DIMC + c)) * MM + m0 + ms;
            float r0 = x_re[base],      i0 = x_im[base];
            float r1 = x_re[base + MM], i1 = x_im[base + MM];
            unsigned rh0 = bf16rne(r0), rh1 = bf16rne(r1);
            unsigned ih0 = bf16rne(i0), ih1 = bf16rne(i1);
            float rl0 = r0 - bf16tof(rh0), rl1 = r1 - bf16tof(rh1);
            float il0 = i0 - bf16tof(ih0), il1 = i1 - bf16tof(ih1);
            Xsh[0 * 640 + ms * 20 + cp] = rh0 | (rh1 << 16);
            Xsh[1 * 640 + ms * 20 + cp] = ih0 | (ih1 << 16);
            Xsh[2 * 640 + ms * 20 + cp] = bf16rne(rl0) | (bf16rne(rl1) << 16);
            Xsh[3 * 640 + ms * 20 + cp] = bf16rne(il0) | (bf16rne(il1) << 16);
        }
        __syncthreads();

        int mrow = mt * 16 + col;
        short8 Xrh = *(const short8*)&Xsh[0 * 640 + mrow * 20 + quad * 4];
        short8 Xih = *(const short8*)&Xsh[1 * 640 + mrow * 20 + quad * 4];
        short8 Xrl = *(const short8*)&Xsh[2 * 640 + mrow * 20 + quad * 4];
        short8 Xil = *(const short8*)&Xsh[3 * 640 + mrow * 20 + quad * 4];

#pragma unroll
        for (int ot = 0; ot < 6; ++ot) {
            int orow = (og * 6 + ot) * 16 + col;
            frag8 Arh, Aih, Arl, Ail, Anh, Anl;
            Arh.s = *(const short8*)&Wsh[(0 * OPAD + orow) * 16 + quad * 4];
            Aih.s = *(const short8*)&Wsh[(1 * OPAD + orow) * 16 + quad * 4];
            Arl.s = *(const short8*)&Wsh[(2 * OPAD + orow) * 16 + quad * 4];
            Ail.s = *(const short8*)&Wsh[(3 * OPAD + orow) * 16 + quad * 4];
#pragma unroll
            for (int i = 0; i < 4; ++i) {
                Anh.u[i] = Aih.u[i] ^ 0x80008000u;
                Anl.u[i] = Ail.u[i] ^ 0x80008000u;
            }
            accR[ot] = __builtin_amdgcn_mfma_f32_16x16x32_bf16(Arh.s, Xrh, accR[ot], 0, 0, 0);
            accR[ot] = __builtin_amdgcn_mfma_f32_16x16x32_bf16(Anh.s, Xih, accR[ot], 0, 0, 0);
            accR[ot] = __builtin_amdgcn_mfma_f32_16x16x32_bf16(Arh.s, Xrl, accR[ot], 0, 0, 0);
            accR[ot] = __builtin_amdgcn_mfma_f32_16x16x32_bf16(Anh.s, Xil, accR[ot], 0, 0, 0);
            accR[ot] = __builtin_amdgcn_mfma_f32_16x16x32_bf16(Arl.s, Xrh, accR[ot], 0, 0, 0);
            accR[ot] = __builtin_amdgcn_mfma_f32_16x16x32_bf16(Anl.s, Xih, accR[ot], 0, 0, 0);
            accI[ot] = __builtin_amdgcn_mfma_f32_16x16x32_bf16(Arh.s, Xih, accI[ot], 0, 0, 0);
            accI[ot] = __builtin_amdgcn_mfma_f32_16x16x32_bf16(Aih.s, Xrh, accI[ot], 0, 0, 0);
            accI[ot] = __builtin_amdgcn_mfma_f32_16x16x32_bf16(Arh.s, Xil, accI[ot], 0, 0, 0);
            accI[ot] = __builtin_amdgcn_mfma_f32_16x16x32_bf16(Aih.s, Xrl, accI[ot], 0, 0, 0);
            accI[ot] = __builtin_amdgcn_mfma_f32_16x16x32_bf16(Arl.s, Xih, accI[ot], 0, 0, 0);
            accI[ot] = __builtin_amdgcn_mfma_f32_16x16x32_bf16(Ail.s, Xrh, accI[ot], 0, 0, 0);
        }
        __syncthreads();
    }

#pragma unroll
    for (int ot = 0; ot < 6; ++ot) {
        int gto = og * 6 + ot;
        if (gto >= 11) continue;
#pragma unroll
        for (int r = 0; r < 4; ++r) {
            int o = gto * 16 + quad * 4 + r;
            O[((size_t)(b * NCH + o)) * MM + m0 + mt * 16 + col] =
                make_float2(accR[ot][r], accI[ot][r]);
        }
    }
}

// ---------------------------------------------------------------------------
// K2: complex BN stats (double accumulation)  (unchanged)
// ---------------------------------------------------------------------------
__global__ __launch_bounds__(256) void k_bnstats(
    const float2* __restrict__ O,
    const float* __restrict__ qs_re, const float* __restrict__ qs_im,
    const float* __restrict__ qb_re, const float* __restrict__ qb_im,
    const float* __restrict__ vs_re, const float* __restrict__ vs_im,
    const float* __restrict__ vb_re, const float* __restrict__ vb_im,
    float4* __restrict__ stats)
{
    const int ch  = blockIdx.x;
    const int o   = (ch < 128) ? ch : (144 + ch - 128);
    const int tid = threadIdx.x;

    double sr = 0, si = 0, sq = 0, sri = 0;
    for (int idx = tid; idx < BB * MM; idx += 256) {
        int b = idx >> 10, m = idx & 1023;
        float2 val = O[((size_t)(b * NCH + o)) * MM + m];
        double r = val.x, ii = val.y;
        sr += r; si += ii; sq += r * r - ii * ii; sri += r * ii;
    }
    __shared__ double red[4][256];
    red[0][tid] = sr; red[1][tid] = si; red[2][tid] = sq; red[3][tid] = sri;
    __syncthreads();
    for (int s = 128; s > 0; s >>= 1) {
        if (tid < s) {
            red[0][tid] += red[0][tid + s]; red[1][tid] += red[1][tid + s];
            red[2][tid] += red[2][tid + s]; red[3][tid] += red[3][tid + s];
        }
        __syncthreads();
    }
    if (tid == 0) {
        const double inv = 1.0 / (double)(BB * MM);
        double mr = red[0][0] * inv, mi = red[1][0] * inv;
        double vr = red[2][0] * inv - (mr * mr - mi * mi) + EPSV;
        double vi = 2.0 * (red[3][0] * inv - mr * mi);
        double rad = sqrt(vr * vr + vi * vi);
        double wr  = sqrt(fmax(0.5 * (rad + vr), 0.0));
        double wi  = sqrt(fmax(0.5 * (rad - vr), 0.0));
        if (vi < 0) wi = -wi;
        double den = wr * wr + wi * wi;
        double ivr = wr / den, ivi = -wi / den;
        double scr, sci, shr, shi;
        if (ch < 128) { scr = qs_re[ch]; sci = qs_im[ch]; shr = qb_re[ch]; shi = qb_im[ch]; }
        else { int i2 = ch - 128; scr = vs_re[i2]; sci = vs_im[i2]; shr = vb_re[i2]; shi = vb_im[i2]; }
        double Ar = scr * ivr - sci * ivi;
        double Ai = scr * ivi + sci * ivr;
        double Br = shr - (Ar * mr - Ai * mi);
        double Bi = shi - (Ar * mi + Ai * mr);
        stats[ch] = make_float4((float)Ar, (float)Ai, (float)Br, (float)Bi);
    }
}

// ---------------------------------------------------------------------------
// K3a: apply BN affine in place; v channels also emit bf16 planes (unchanged)
// ---------------------------------------------------------------------------
__global__ __launch_bounds__(256) void k_bnapply(
    const float4* __restrict__ stats, float2* __restrict__ O,
    unsigned* __restrict__ VR, unsigned* __restrict__ VI)
{
    int ch = blockIdx.x, b = blockIdx.y;
    int o  = (ch < 128) ? ch : (144 + ch - 128);
    float4 s = stats[ch];
    float2* row = O + ((size_t)(b * NCH + o)) * MM;
    int tid = threadIdx.x;
    for (int mm = tid; mm < 512; mm += 256) {
        float4 two = *(float4*)&row[2 * mm];
        float nr0 = s.x * two.x - s.y * two.y + s.z;
        float ni0 = s.x * two.y + s.y * two.x + s.w;
        float nr1 = s.x * two.z - s.y * two.w + s.z;
        float ni1 = s.x * two.w + s.y * two.z + s.w;
        *(float4*)&row[2 * mm] = make_float4(nr0, ni0, nr1, ni1);
        if (ch >= 128) {
            int bv = b * VD + (ch - 128);
            VR[(size_t)bv * 512 + mm] = bf16rne(nr0) | (bf16rne(nr1) << 16);
            VI[(size_t)bv * 512 + mm] = bf16rne(ni0) | (bf16rne(ni1) << 16);
        }
    }
}

// ---------------------------------------------------------------------------
// k_softlam: softmax over m of |k| fused with content lambda  (unchanged)
// ---------------------------------------------------------------------------
__global__ __launch_bounds__(256) void k_softlam(
    const float2* __restrict__ O, float2* __restrict__ lamc)
{
    int kc = blockIdx.x, b = blockIdx.y;
    const float2* row = O + ((size_t)(b * NCH + 128 + kc)) * MM;
    int tid = threadIdx.x;
    __shared__ float red[256];
    __shared__ float skl[1024];

    float mag[4]; float mx = -1e30f;
#pragma unroll
    for (int j = 0; j < 4; ++j) {
        float2 v = row[tid + j * 256];
        mag[j] = sqrtf(v.x * v.x + v.y * v.y);
        mx = fmaxf(mx, mag[j]);
    }
    red[tid] = mx; __syncthreads();
    for (int s = 128; s > 0; s >>= 1) { if (tid < s) red[tid] = fmaxf(red[tid], red[tid + s]); __syncthreads(); }
    mx = red[0]; __syncthreads();
    float e[4]; float sum = 0.f;
#pragma unroll
    for (int j = 0; j < 4; ++j) { e[j] = expf(mag[j] - mx); sum += e[j]; }
    red[tid] = sum; __syncthreads();
    for (int s = 128; s > 0; s >>= 1) { if (tid < s) red[tid] += red[tid + s]; __syncthreads(); }
    float inv = 1.f / red[0];
#pragma unroll
    for (int j = 0; j < 4; ++j) skl[tid + j * 256] = e[j] * inv;
    __syncthreads();

    int v = tid >> 3, s8 = tid & 7;
    const float2* vrow = O + ((size_t)(b * NCH + 144 + v)) * MM;
    float ar = 0.f, ai = 0.f;
    for (int i = 0; i < 128; ++i) {
        int m = s8 * 128 + i;
        float wgt = skl[m]; float2 vv = vrow[m];
        ar += wgt * vv.x; ai += wgt * vv.y;
    }
    __shared__ float2 part[32][8];
    part[v][s8] = make_float2(ar, ai);
    __syncthreads();
    if (tid < 32) {
        float2 t = part[tid][0];
#pragma unroll
        for (int j = 1; j < 8; ++j) { t.x += part[tid][j].x; t.y += part[tid][j].y; }
        lamc[((size_t)(b * KD + kc)) * VD + tid] = t;
    }
}

// ---------------------------------------------------------------------------
// k_eprep — repack emb into embC[k][di][dj] = u32( bf16(im)<<16 | bf16(re) )
// ---------------------------------------------------------------------------
__global__ __launch_bounds__(256) void k_eprep(
    const float* __restrict__ er, const float* __restrict__ ei,
    unsigned* __restrict__ embC)
{
    int i = blockIdx.x * 256 + threadIdx.x;
    if (i >= 63 * 63 * 16) return;
    int kk = i & 15;
    int rest = i >> 4;
    int dj = rest % 63;
    int di = rest / 63;
    embC[(kk * 63 + di) * 63 + dj] = bf16rne(er[i]) | (bf16rne(ei[i]) << 16);
}

// ---------------------------------------------------------------------------
// k_main (R6): bf16 MFMA for lam_p + fused epilogue.
// R6 changes vs R5:
//  - c-loop #pragma unroll 1: the fully-unrolled ~50 KB body overflowed the
//    32 KB I$ (theory for R4/R5's 145 µs of no-pipe-busy stall).
//  - A-gather window trick: one 12-dword load window per (lane, chunk) serves
//    all 4 g (overlapping 8-dword windows, dj0 shifts by 1/g) — 3 loads
//    instead of 8, compile-time perm selection.
//  - __launch_bounds__(256,3): 3 blocks/CU for latency hiding.
// ---------------------------------------------------------------------------
__global__ __launch_bounds__(256, 3) void k_main(
    const float2* __restrict__ O,
    const unsigned* __restrict__ embC,
    const unsigned* __restrict__ VbfR,
    const unsigned* __restrict__ VbfI,
    const float2* __restrict__ lamc,
    float* __restrict__ out, int cplx)
{
    const int tid  = threadIdx.x;
    const int w    = tid >> 6;
    const int lane = tid & 63;
    const int quad = lane >> 4;
    const int col  = lane & 15;

    const int n0  = blockIdx.x * 4;
    const int bvq = blockIdx.y;        // 0..3, 128 bv rows each
    const int b0  = bvq * 4;
    const int ni  = n0 >> 5;
    const int nj0 = n0 & 31;

    __shared__ __align__(16) unsigned shraw[4096];   // V stage 16 KB / lamt
    unsigned* vsR = shraw;                            // [128][16]
    unsigned* vsI = shraw + 2048;
    float2*   lamt = (float2*)shraw;                  // [16k][128bv]
    __shared__ __align__(16) float2 qsh[2048];        // [bl(4)][ch(128)][g(4)]

    // stage q tile (BN already applied in place)
#pragma unroll
    for (int it = 0; it < 8; ++it) {
        int idx = it * 256 + tid;
        int g = idx & 3, ch = (idx >> 2) & 127, bl = idx >> 9;
        qsh[idx] = O[((size_t)((b0 + bl) * NCH + ch)) * MM + n0 + g];
    }

    f32x4 accr[4][2], acci[4][2];
#pragma unroll
    for (int g = 0; g < 4; ++g)
#pragma unroll
        for (int t = 0; t < 2; ++t) {
            accr[g][t] = (f32x4){0.f, 0.f, 0.f, 0.f};
            acci[g][t] = (f32x4){0.f, 0.f, 0.f, 0.f};
        }

    const unsigned* vsrcR = VbfR + (size_t)(bvq * 128) * 512;
    const unsigned* vsrcI = VbfI + (size_t)(bvq * 128) * 512;
    const int rowLane = lane >> 2;
    const int moff    = (lane & 3) * 4;
    const int base_dj = quad * 8 + 28 - nj0;          // in [0, 52]
    const unsigned* apBase = embC + (size_t)(col * 63) * 63 + base_dj;

#pragma unroll 1
    for (int c = 0; c < 32; ++c) {
        // ---- stage V chunk: wave w stages rows [w*32, w*32+32), both planes
        {
            const unsigned* gR = vsrcR + ((size_t)(w * 32 + rowLane)) * 512 + c * 16 + moff;
            const unsigned* gI = vsrcI + ((size_t)(w * 32 + rowLane)) * 512 + c * 16 + moff;
            GL2LDS16(gR,                      vsR + w * 512);
            GL2LDS16(gR + (size_t)16 * 512,   vsR + w * 512 + 256);
            GL2LDS16(gI,                      vsI + w * 512);
            GL2LDS16(gI + (size_t)16 * 512,   vsI + w * 512 + 256);
        }

        // ---- A-window load (independent of LDS; issue before barrier)
        const int di = c - ni + 31;                    // in [0, 62]
        const unsigned* ap = apBase + di * 63;
        u32x4a W0 = *(const u32x4a*)ap;
        u32x4a W1 = *(const u32x4a*)(ap + 4);
        u32x4a W2 = *(const u32x4a*)(ap + 8);
        unsigned W[12] = { W0.x, W0.y, W0.z, W0.w,
                           W1.x, W1.y, W1.z, W1.w,
                           W2.x, W2.y, W2.z, W2.w };

        __syncthreads();

        // ---- B-fragments (reused across 4 n)
        short8 Br[2], Bi[2];
#pragma unroll
        for (int t = 0; t < 2; ++t) {
            int rowb = w * 32 + t * 16 + col;
            Br[t] = *(const short8*)&vsR[rowb * 16 + quad * 4];
            Bi[t] = *(const short8*)&vsI[rowb * 16 + quad * 4];
        }

#pragma unroll
        for (int g = 0; g < 4; ++g) {
            const int o = 3 - g;                       // compile-time
            union { unsigned u[4]; short8 s; } Rr, Ri, Rin;
            Rr.u[0] = __builtin_amdgcn_perm(W[o + 1], W[o + 0], 0x05040100u);
            Rr.u[1] = __builtin_amdgcn_perm(W[o + 3], W[o + 2], 0x05040100u);
            Rr.u[2] = __builtin_amdgcn_perm(W[o + 5], W[o + 4], 0x05040100u);
            Rr.u[3] = __builtin_amdgcn_perm(W[o + 7], W[o + 6], 0x05040100u);
            Ri.u[0] = __builtin_amdgcn_perm(W[o + 1], W[o + 0], 0x07060302u);
            Ri.u[1] = __builtin_amdgcn_perm(W[o + 3], W[o + 2], 0x07060302u);
            Ri.u[2] = __builtin_amdgcn_perm(W[o + 5], W[o + 4], 0x07060302u);
            Ri.u[3] = __builtin_amdgcn_perm(W[o + 7], W[o + 6], 0x07060302u);
            Rin.u[0] = Ri.u[0] ^ 0x80008000u;
            Rin.u[1] = Ri.u[1] ^ 0x80008000u;
            Rin.u[2] = Ri.u[2] ^ 0x80008000u;
            Rin.u[3] = Ri.u[3] ^ 0x80008000u;
#pragma unroll
            for (int t = 0; t < 2; ++t) {
                accr[g][t] = __builtin_amdgcn_mfma_f32_16x16x32_bf16(Rr.s,  Br[t], accr[g][t], 0, 0, 0);
                accr[g][t] = __builtin_amdgcn_mfma_f32_16x16x32_bf16(Rin.s, Bi[t], accr[g][t], 0, 0, 0);
                acci[g][t] = __builtin_amdgcn_mfma_f32_16x16x32_bf16(Rr.s,  Bi[t], acci[g][t], 0, 0, 0);
                acci[g][t] = __builtin_amdgcn_mfma_f32_16x16x32_bf16(Ri.s,  Br[t], acci[g][t], 0, 0, 0);
            }
        }
        __syncthreads();
    }

    // ---- hoist lam_c (g-invariant)
    float2 lcv[2][4];
#pragma unroll
    for (int t = 0; t < 2; ++t) {
        int bvl = w * 32 + t * 16 + col;
        int bloc = b0 + (bvl >> 5), v = bvl & 31;
#pragma unroll
        for (int r = 0; r < 4; ++r)
            lcv[t][r] = lamc[((size_t)(bloc * KD + quad * 4 + r)) * VD + v];
    }

    // ---- epilogue (fully unrolled; g compile-time)
    const int col128 = tid & 127;
    const int hb = (tid >> 7) * 4;          // 4 heads per thread-half
    const int bl = col128 >> 5, vY = col128 & 31;
    const int bY = b0 + bl;
    float2* op2 = (float2*)out;
#pragma unroll
    for (int g = 0; g < 4; ++g) {
        __syncthreads();
#pragma unroll
        for (int t = 0; t < 2; ++t) {
            int bvl = w * 32 + t * 16 + col;
#pragma unroll
            for (int r = 0; r < 4; ++r) {
                int k = quad * 4 + r;
                lamt[k * 128 + bvl] = make_float2(accr[g][t][r] + lcv[t][r].x,
                                                  acci[g][t][r] + lcv[t][r].y);
            }
        }
        __syncthreads();
        float yr[4], yi[4];
#pragma unroll
        for (int h = 0; h < 4; ++h) { yr[h] = 0.f; yi[h] = 0.f; }
#pragma unroll
        for (int k = 0; k < 16; ++k) {
            float2 l = lamt[k * 128 + col128];
#pragma unroll
            for (int h = 0; h < 4; ++h) {
                float2 q = qsh[(bl * 128 + (hb + h) * 16 + k) * 4 + g];
                yr[h] += q.x * l.x - q.y * l.y;
                yi[h] += q.x * l.y + q.y * l.x;
            }
        }
        int n = n0 + g;
        if (cplx) {
#pragma unroll
            for (int h = 0; h < 4; ++h)
                op2[((size_t)(bY * 256 + (hb + h) * 32 + vY)) * MM + n] = make_float2(yr[h], yi[h]);
        } else {
#pragma unroll
            for (int h = 0; h < 4; ++h)
                out[((size_t)(bY * 256 + (hb + h) * 32 + vY)) * MM + n] = yr[h];
        }
    }
}

// ---------------------------------------------------------------------------
extern "C" void kernel_launch(void* const* d_in, const int* in_sizes, int n_in,
                              void* d_out, int out_size, void* d_ws, size_t ws_size,
                              hipStream_t stream)
{
    const float* x_re  = (const float*)d_in[0];
    const float* x_im  = (const float*)d_in[1];
    const float* wq_re = (const float*)d_in[2];
    const float* wq_im = (const float*)d_in[3];
    const float* wk_re = (const float*)d_in[4];
    const float* wk_im = (const float*)d_in[5];
    const float* wv_re = (const float*)d_in[6];
    const float* wv_im = (const float*)d_in[7];
    const float* qs_re = (const float*)d_in[8];
    const float* qs_im = (const float*)d_in[9];
    const float* qb_re = (const float*)d_in[10];
    const float* qb_im = (const float*)d_in[11];
    const float* vs_re = (const float*)d_in[12];
    const float* vs_im = (const float*)d_in[13];
    const float* vb_re = (const float*)d_in[14];
    const float* vb_im = (const float*)d_in[15];
    const float* emb_re = (const float*)d_in[16];
    const float* emb_im = (const float*)d_in[17];

    float* ws = (float*)d_ws;
    const size_t O_OFF  = 0;                                     // 5,767,168
    const size_t ST_OFF = O_OFF + (size_t)BB * NCH * MM * 2;     // 640
    const size_t LC_OFF = ST_OFF + 640;                          // 16,384
    const size_t EC_OFF = LC_OFF + 16384;                        // 63,504 + 16 pad
    const size_t WP_OFF = EC_OFF + 63520;                        // 98,304 (Wpk)
    const size_t VR_OFF = WP_OFF + 98304;                        // 262,144
    const size_t VI_OFF = VR_OFF + 262144;                       // 262,144

    float2*   O     = (float2*)(ws + O_OFF);
    float4*   stats = (float4*)(ws + ST_OFF);
    float2*   lamc  = (float2*)(ws + LC_OFF);
    unsigned* embC  = (unsigned*)(ws + EC_OFF);
    unsigned* Wpk   = (unsigned*)(ws + WP_OFF);
    unsigned* VbfR  = (unsigned*)(ws + VR_OFF);
    unsigned* VbfI  = (unsigned*)(ws + VI_OFF);
    float*    outp  = (float*)d_out;

    int cplx = (out_size >= 2 * BB * 256 * MM) ? 1 : 0;

    k_wprep<<<dim3(96), 256, 0, stream>>>(wq_re, wq_im, wk_re, wk_im,
                                          wv_re, wv_im, Wpk);
    k_eprep<<<dim3(249), 256, 0, stream>>>(emb_re, emb_im, embC);
    k_proj<<<dim3(32, BB), 256, 0, stream>>>(x_re, x_im, Wpk, O);
    k_bnstats<<<dim3(160), 256, 0, stream>>>(O, qs_re, qs_im, qb_re, qb_im,
                                             vs_re, vs_im, vb_re, vb_im, stats);
    k_bnapply<<<dim3(160, BB), 256, 0, stream>>>(stats, O, VbfR, VbfI);
    k_softlam<<<dim3(KD, BB), 256, 0, stream>>>(O, lamc);
    k_main<<<dim3(256, 4), 256, 0, stream>>>(O, embC, VbfR, VbfI, lamc, outp, cplx);
}

// Round 7
// 284.400 us; speedup vs baseline: 1.2469x; 1.1604x over previous
//
#include <hip/hip_runtime.h>
#include <math.h>

// Problem constants
#define DIMC 256   // input channels
#define NCH  176   // 128 q + 16 k + 32 v output channels
#define MM   1024  // N2 spatial
#define BB   16    // batch
#define KD   16    // DIM_K
#define HH   8     // heads
#define VD   32    // DIM_V
#define EPSV 1e-5
#define OPAD 192   // padded output channels for MFMA proj (12 o-tiles)

typedef short short8 __attribute__((ext_vector_type(8)));
typedef float f32x4  __attribute__((ext_vector_type(4)));
typedef unsigned u32x4v __attribute__((ext_vector_type(4)));
typedef u32x4v u32x4a __attribute__((aligned(4)));   // 4-byte-aligned dwordx4

union frag8 { unsigned u[4]; short8 s; u32x4v v; };

__device__ __forceinline__ unsigned bf16rne(float f) {
    unsigned u = __float_as_uint(f);
    unsigned r = u + 0x7FFFu + ((u >> 16) & 1u);
    return r >> 16;
}
__device__ __forceinline__ float bf16tof(unsigned h) {
    return __uint_as_float(h << 16);
}

#define GL2LDS16(g, l) __builtin_amdgcn_global_load_lds( \
    (const __attribute__((address_space(1))) unsigned*)(g), \
    (__attribute__((address_space(3))) unsigned*)(l), 16, 0, 0)
#define GL2LDS4(g, l) __builtin_amdgcn_global_load_lds( \
    (const __attribute__((address_space(1))) unsigned*)(g), \
    (__attribute__((address_space(3))) unsigned*)(l), 4, 0, 0)

// ---------------------------------------------------------------------------
// k_wprep: pack W (q|k|v concat, padded to 192 rows) into 4 planes of
// [192][128] u32 (re_hi / im_hi / re_lo / im_lo, split-bf16).  (unchanged)
// ---------------------------------------------------------------------------
__global__ __launch_bounds__(256) void k_wprep(
    const float* __restrict__ wq_re, const float* __restrict__ wq_im,
    const float* __restrict__ wk_re, const float* __restrict__ wk_im,
    const float* __restrict__ wv_re, const float* __restrict__ wv_im,
    unsigned* __restrict__ Wpk)
{
    int idx = blockIdx.x * 256 + threadIdx.x;   // 0..24575
    if (idx >= OPAD * 128) return;
    int o = idx >> 7, j = idx & 127;
    int c0 = 2 * j;
    float r0 = 0.f, r1 = 0.f, i0 = 0.f, i1 = 0.f;
    if (o < 128) {
        r0 = wq_re[o * DIMC + c0]; r1 = wq_re[o * DIMC + c0 + 1];
        i0 = wq_im[o * DIMC + c0]; i1 = wq_im[o * DIMC + c0 + 1];
    } else if (o < 144) {
        int oo = o - 128;
        r0 = wk_re[oo * DIMC + c0]; r1 = wk_re[oo * DIMC + c0 + 1];
        i0 = wk_im[oo * DIMC + c0]; i1 = wk_im[oo * DIMC + c0 + 1];
    } else if (o < 176) {
        int oo = o - 144;
        r0 = wv_re[oo * DIMC + c0]; r1 = wv_re[oo * DIMC + c0 + 1];
        i0 = wv_im[oo * DIMC + c0]; i1 = wv_im[oo * DIMC + c0 + 1];
    }
    unsigned rh0 = bf16rne(r0), rh1 = bf16rne(r1);
    unsigned ih0 = bf16rne(i0), ih1 = bf16rne(i1);
    float rl0 = r0 - bf16tof(rh0), rl1 = r1 - bf16tof(rh1);
    float il0 = i0 - bf16tof(ih0), il1 = i1 - bf16tof(ih1);
    Wpk[0 * OPAD * 128 + idx] = rh0 | (rh1 << 16);
    Wpk[1 * OPAD * 128 + idx] = ih0 | (ih1 << 16);
    Wpk[2 * OPAD * 128 + idx] = bf16rne(rl0) | (bf16rne(rl1) << 16);
    Wpk[3 * OPAD * 128 + idx] = bf16rne(il0) | (bf16rne(il1) << 16);
}

// ---------------------------------------------------------------------------
// k_proj (MFMA, split-bf16, kk-loop not unrolled).  (unchanged from R6)
// ---------------------------------------------------------------------------
__global__ __launch_bounds__(256, 2) void k_proj(
    const float* __restrict__ x_re, const float* __restrict__ x_im,
    const unsigned* __restrict__ Wpk,
    float2* __restrict__ O)
{
    const int m0  = blockIdx.x * 32;
    const int b   = blockIdx.y;
    const int tid = threadIdx.x;
    const int w    = tid >> 6;
    const int lane = tid & 63;
    const int quad = lane >> 4;
    const int col  = lane & 15;
    const int mt = w & 1, og = w >> 1;

    __shared__ __align__(16) unsigned Wsh[4 * OPAD * 16];  // 48 KB
    __shared__ __align__(16) unsigned Xsh[4 * 32 * 20];    // 10 KB

    f32x4 accR[6], accI[6];
#pragma unroll
    for (int t = 0; t < 6; ++t) {
        accR[t] = (f32x4){0.f, 0.f, 0.f, 0.f};
        accI[t] = (f32x4){0.f, 0.f, 0.f, 0.f};
    }

    const int ms = tid & 31;
    const int cps = tid >> 5;

#pragma unroll 1
    for (int kk = 0; kk < 8; ++kk) {
#pragma unroll
        for (int p = 0; p < 12; ++p) {
            int idx = p * 256 + tid;
            int plane = idx / 768;
            int rem = idx - plane * 768;
            int row = rem >> 2, seg = rem & 3;
            u32x4v d = *(const u32x4v*)&Wpk[(size_t)plane * (OPAD * 128) + row * 128 + kk * 16 + seg * 4];
            *(u32x4v*)&Wsh[(plane * OPAD + row) * 16 + seg * 4] = d;
        }
#pragma unroll
        for (int p = 0; p < 2; ++p) {
            int cp = cps + p * 8;
            int c  = kk * 32 + cp * 2;
            size_t base = ((size_t)(b * DIMC + c)) * MM + m0 + ms;
            float r0 = x_re[base],      i0 = x_im[base];
            float r1 = x_re[base + MM], i1 = x_im[base + MM];
            unsigned rh0 = bf16rne(r0), rh1 = bf16rne(r1);
            unsigned ih0 = bf16rne(i0), ih1 = bf16rne(i1);
            float rl0 = r0 - bf16tof(rh0), rl1 = r1 - bf16tof(rh1);
            float il0 = i0 - bf16tof(ih0), il1 = i1 - bf16tof(ih1);
            Xsh[0 * 640 + ms * 20 + cp] = rh0 | (rh1 << 16);
            Xsh[1 * 640 + ms * 20 + cp] = ih0 | (ih1 << 16);
            Xsh[2 * 640 + ms * 20 + cp] = bf16rne(rl0) | (bf16rne(rl1) << 16);
            Xsh[3 * 640 + ms * 20 + cp] = bf16rne(il0) | (bf16rne(il1) << 16);
        }
        __syncthreads();

        int mrow = mt * 16 + col;
        short8 Xrh = *(const short8*)&Xsh[0 * 640 + mrow * 20 + quad * 4];
        short8 Xih = *(const short8*)&Xsh[1 * 640 + mrow * 20 + quad * 4];
        short8 Xrl = *(const short8*)&Xsh[2 * 640 + mrow * 20 + quad * 4];
        short8 Xil = *(const short8*)&Xsh[3 * 640 + mrow * 20 + quad * 4];

#pragma unroll
        for (int ot = 0; ot < 6; ++ot) {
            int orow = (og * 6 + ot) * 16 + col;
            frag8 Arh, Aih, Arl, Ail, Anh, Anl;
            Arh.s = *(const short8*)&Wsh[(0 * OPAD + orow) * 16 + quad * 4];
            Aih.s = *(const short8*)&Wsh[(1 * OPAD + orow) * 16 + quad * 4];
            Arl.s = *(const short8*)&Wsh[(2 * OPAD + orow) * 16 + quad * 4];
            Ail.s = *(const short8*)&Wsh[(3 * OPAD + orow) * 16 + quad * 4];
#pragma unroll
            for (int i = 0; i < 4; ++i) {
                Anh.u[i] = Aih.u[i] ^ 0x80008000u;
                Anl.u[i] = Ail.u[i] ^ 0x80008000u;
            }
            accR[ot] = __builtin_amdgcn_mfma_f32_16x16x32_bf16(Arh.s, Xrh, accR[ot], 0, 0, 0);
            accR[ot] = __builtin_amdgcn_mfma_f32_16x16x32_bf16(Anh.s, Xih, accR[ot], 0, 0, 0);
            accR[ot] = __builtin_amdgcn_mfma_f32_16x16x32_bf16(Arh.s, Xrl, accR[ot], 0, 0, 0);
            accR[ot] = __builtin_amdgcn_mfma_f32_16x16x32_bf16(Anh.s, Xil, accR[ot], 0, 0, 0);
            accR[ot] = __builtin_amdgcn_mfma_f32_16x16x32_bf16(Arl.s, Xrh, accR[ot], 0, 0, 0);
            accR[ot] = __builtin_amdgcn_mfma_f32_16x16x32_bf16(Anl.s, Xih, accR[ot], 0, 0, 0);
            accI[ot] = __builtin_amdgcn_mfma_f32_16x16x32_bf16(Arh.s, Xih, accI[ot], 0, 0, 0);
            accI[ot] = __builtin_amdgcn_mfma_f32_16x16x32_bf16(Aih.s, Xrh, accI[ot], 0, 0, 0);
            accI[ot] = __builtin_amdgcn_mfma_f32_16x16x32_bf16(Arh.s, Xil, accI[ot], 0, 0, 0);
            accI[ot] = __builtin_amdgcn_mfma_f32_16x16x32_bf16(Aih.s, Xrl, accI[ot], 0, 0, 0);
            accI[ot] = __builtin_amdgcn_mfma_f32_16x16x32_bf16(Arl.s, Xih, accI[ot], 0, 0, 0);
            accI[ot] = __builtin_amdgcn_mfma_f32_16x16x32_bf16(Ail.s, Xrh, accI[ot], 0, 0, 0);
        }
        __syncthreads();
    }

#pragma unroll
    for (int ot = 0; ot < 6; ++ot) {
        int gto = og * 6 + ot;
        if (gto >= 11) continue;
#pragma unroll
        for (int r = 0; r < 4; ++r) {
            int o = gto * 16 + quad * 4 + r;
            O[((size_t)(b * NCH + o)) * MM + m0 + mt * 16 + col] =
                make_float2(accR[ot][r], accI[ot][r]);
        }
    }
}

// ---------------------------------------------------------------------------
// K2: complex BN stats (double accumulation)  (unchanged)
// ---------------------------------------------------------------------------
__global__ __launch_bounds__(256) void k_bnstats(
    const float2* __restrict__ O,
    const float* __restrict__ qs_re, const float* __restrict__ qs_im,
    const float* __restrict__ qb_re, const float* __restrict__ qb_im,
    const float* __restrict__ vs_re, const float* __restrict__ vs_im,
    const float* __restrict__ vb_re, const float* __restrict__ vb_im,
    float4* __restrict__ stats)
{
    const int ch  = blockIdx.x;
    const int o   = (ch < 128) ? ch : (144 + ch - 128);
    const int tid = threadIdx.x;

    double sr = 0, si = 0, sq = 0, sri = 0;
    for (int idx = tid; idx < BB * MM; idx += 256) {
        int b = idx >> 10, m = idx & 1023;
        float2 val = O[((size_t)(b * NCH + o)) * MM + m];
        double r = val.x, ii = val.y;
        sr += r; si += ii; sq += r * r - ii * ii; sri += r * ii;
    }
    __shared__ double red[4][256];
    red[0][tid] = sr; red[1][tid] = si; red[2][tid] = sq; red[3][tid] = sri;
    __syncthreads();
    for (int s = 128; s > 0; s >>= 1) {
        if (tid < s) {
            red[0][tid] += red[0][tid + s]; red[1][tid] += red[1][tid + s];
            red[2][tid] += red[2][tid + s]; red[3][tid] += red[3][tid + s];
        }
        __syncthreads();
    }
    if (tid == 0) {
        const double inv = 1.0 / (double)(BB * MM);
        double mr = red[0][0] * inv, mi = red[1][0] * inv;
        double vr = red[2][0] * inv - (mr * mr - mi * mi) + EPSV;
        double vi = 2.0 * (red[3][0] * inv - mr * mi);
        double rad = sqrt(vr * vr + vi * vi);
        double wr  = sqrt(fmax(0.5 * (rad + vr), 0.0));
        double wi  = sqrt(fmax(0.5 * (rad - vr), 0.0));
        if (vi < 0) wi = -wi;
        double den = wr * wr + wi * wi;
        double ivr = wr / den, ivi = -wi / den;
        double scr, sci, shr, shi;
        if (ch < 128) { scr = qs_re[ch]; sci = qs_im[ch]; shr = qb_re[ch]; shi = qb_im[ch]; }
        else { int i2 = ch - 128; scr = vs_re[i2]; sci = vs_im[i2]; shr = vb_re[i2]; shi = vb_im[i2]; }
        double Ar = scr * ivr - sci * ivi;
        double Ai = scr * ivi + sci * ivr;
        double Br = shr - (Ar * mr - Ai * mi);
        double Bi = shi - (Ar * mi + Ai * mr);
        stats[ch] = make_float4((float)Ar, (float)Ai, (float)Br, (float)Bi);
    }
}

// ---------------------------------------------------------------------------
// K3a: apply BN affine in place; v channels also emit bf16 planes (unchanged)
// ---------------------------------------------------------------------------
__global__ __launch_bounds__(256) void k_bnapply(
    const float4* __restrict__ stats, float2* __restrict__ O,
    unsigned* __restrict__ VR, unsigned* __restrict__ VI)
{
    int ch = blockIdx.x, b = blockIdx.y;
    int o  = (ch < 128) ? ch : (144 + ch - 128);
    float4 s = stats[ch];
    float2* row = O + ((size_t)(b * NCH + o)) * MM;
    int tid = threadIdx.x;
    for (int mm = tid; mm < 512; mm += 256) {
        float4 two = *(float4*)&row[2 * mm];
        float nr0 = s.x * two.x - s.y * two.y + s.z;
        float ni0 = s.x * two.y + s.y * two.x + s.w;
        float nr1 = s.x * two.z - s.y * two.w + s.z;
        float ni1 = s.x * two.w + s.y * two.z + s.w;
        *(float4*)&row[2 * mm] = make_float4(nr0, ni0, nr1, ni1);
        if (ch >= 128) {
            int bv = b * VD + (ch - 128);
            VR[(size_t)bv * 512 + mm] = bf16rne(nr0) | (bf16rne(nr1) << 16);
            VI[(size_t)bv * 512 + mm] = bf16rne(ni0) | (bf16rne(ni1) << 16);
        }
    }
}

// ---------------------------------------------------------------------------
// k_softlam: softmax over m of |k| fused with content lambda  (unchanged)
// ---------------------------------------------------------------------------
__global__ __launch_bounds__(256) void k_softlam(
    const float2* __restrict__ O, float2* __restrict__ lamc)
{
    int kc = blockIdx.x, b = blockIdx.y;
    const float2* row = O + ((size_t)(b * NCH + 128 + kc)) * MM;
    int tid = threadIdx.x;
    __shared__ float red[256];
    __shared__ float skl[1024];

    float mag[4]; float mx = -1e30f;
#pragma unroll
    for (int j = 0; j < 4; ++j) {
        float2 v = row[tid + j * 256];
        mag[j] = sqrtf(v.x * v.x + v.y * v.y);
        mx = fmaxf(mx, mag[j]);
    }
    red[tid] = mx; __syncthreads();
    for (int s = 128; s > 0; s >>= 1) { if (tid < s) red[tid] = fmaxf(red[tid], red[tid + s]); __syncthreads(); }
    mx = red[0]; __syncthreads();
    float e[4]; float sum = 0.f;
#pragma unroll
    for (int j = 0; j < 4; ++j) { e[j] = expf(mag[j] - mx); sum += e[j]; }
    red[tid] = sum; __syncthreads();
    for (int s = 128; s > 0; s >>= 1) { if (tid < s) red[tid] += red[tid + s]; __syncthreads(); }
    float inv = 1.f / red[0];
#pragma unroll
    for (int j = 0; j < 4; ++j) skl[tid + j * 256] = e[j] * inv;
    __syncthreads();

    int v = tid >> 3, s8 = tid & 7;
    const float2* vrow = O + ((size_t)(b * NCH + 144 + v)) * MM;
    float ar = 0.f, ai = 0.f;
    for (int i = 0; i < 128; ++i) {
        int m = s8 * 128 + i;
        float wgt = skl[m]; float2 vv = vrow[m];
        ar += wgt * vv.x; ai += wgt * vv.y;
    }
    __shared__ float2 part[32][8];
    part[v][s8] = make_float2(ar, ai);
    __syncthreads();
    if (tid < 32) {
        float2 t = part[tid][0];
#pragma unroll
        for (int j = 1; j < 8; ++j) { t.x += part[tid][j].x; t.y += part[tid][j].y; }
        lamc[((size_t)(b * KD + kc)) * VD + tid] = t;
    }
}

// ---------------------------------------------------------------------------
// k_eprep — repack emb into embC[k][di][dj] = u32( bf16(im)<<16 | bf16(re) )
// ---------------------------------------------------------------------------
__global__ __launch_bounds__(256) void k_eprep(
    const float* __restrict__ er, const float* __restrict__ ei,
    unsigned* __restrict__ embC)
{
    int i = blockIdx.x * 256 + threadIdx.x;
    if (i >= 63 * 63 * 16) return;
    int kk = i & 15;
    int rest = i >> 4;
    int dj = rest % 63;
    int di = rest / 63;
    embC[(kk * 63 + di) * 63 + dj] = bf16rne(er[i]) | (bf16rne(ei[i]) << 16);
}

// ---------------------------------------------------------------------------
// k_main (R7): bf16 MFMA for lam_p + fused epilogue.
// R7 changes vs R6:
//  - A-gather de-scattered: per chunk the block's emb slice (16 k x 48 dj,
//    3 KB) is staged into LDS with coalesced global_load_lds width=4
//    (768 dwords = 3 x 256 lanes exactly); lanes then read their 12-dword
//    window with 3 ds_read_b128. R6 did 3 scattered dwordx4 per lane per
//    chunk (~64 cache lines per wave-instr) — suspected TA-throughput stall
//    invisible to SQ/TCC counters.
//  - __launch_bounds__(256,2): R6's (256,3) forced VGPR=84 and spilled
//    (WRITE_SIZE 285 MB vs 135 MB output).
// ---------------------------------------------------------------------------
__global__ __launch_bounds__(256, 2) void k_main(
    const float2* __restrict__ O,
    const unsigned* __restrict__ embC,
    const unsigned* __restrict__ VbfR,
    const unsigned* __restrict__ VbfI,
    const float2* __restrict__ lamc,
    float* __restrict__ out, int cplx)
{
    const int tid  = threadIdx.x;
    const int w    = tid >> 6;
    const int lane = tid & 63;
    const int quad = lane >> 4;
    const int col  = lane & 15;

    const int n0  = blockIdx.x * 4;
    const int bvq = blockIdx.y;        // 0..3, 128 bv rows each
    const int b0  = bvq * 4;
    const int ni  = n0 >> 5;
    const int nj0 = n0 & 31;

    __shared__ __align__(16) unsigned shraw[4096];   // V stage 16 KB / lamt
    unsigned* vsR = shraw;                            // [128][16]
    unsigned* vsI = shraw + 2048;
    float2*   lamt = (float2*)shraw;                  // [16k][128bv]
    __shared__ __align__(16) unsigned embS[768];      // [16k][48dj] 3 KB
    __shared__ __align__(16) float2 qsh[2048];        // [bl(4)][ch(128)][g(4)]

    // stage q tile (BN already applied in place)
#pragma unroll
    for (int it = 0; it < 8; ++it) {
        int idx = it * 256 + tid;
        int g = idx & 3, ch = (idx >> 2) & 127, bl = idx >> 9;
        qsh[idx] = O[((size_t)((b0 + bl) * NCH + ch)) * MM + n0 + g];
    }

    f32x4 accr[4][2], acci[4][2];
#pragma unroll
    for (int g = 0; g < 4; ++g)
#pragma unroll
        for (int t = 0; t < 2; ++t) {
            accr[g][t] = (f32x4){0.f, 0.f, 0.f, 0.f};
            acci[g][t] = (f32x4){0.f, 0.f, 0.f, 0.f};
        }

    const unsigned* vsrcR = VbfR + (size_t)(bvq * 128) * 512;
    const unsigned* vsrcI = VbfI + (size_t)(bvq * 128) * 512;
    const int rowLane = lane >> 2;
    const int moff    = (lane & 3) * 4;
    const int djBase  = 28 - nj0;                    // >= 0 (nj0 <= 28)

    // per-thread emb staging source offsets (di added per chunk)
    int esrc[3];
#pragma unroll
    for (int it = 0; it < 3; ++it) {
        int dw = it * 256 + tid;                     // 0..767
        int k  = dw / 48, dj2 = dw - k * 48;         // staged row stride 48
        esrc[it] = (k * 63) * 63 + djBase + dj2;     // + di*63 at runtime
    }

#pragma unroll 1
    for (int c = 0; c < 32; ++c) {
        const int di = c - ni + 31;                  // in [0, 62]
        // ---- stage V chunk: wave w stages rows [w*32, w*32+32), both planes
        {
            const unsigned* gR = vsrcR + ((size_t)(w * 32 + rowLane)) * 512 + c * 16 + moff;
            const unsigned* gI = vsrcI + ((size_t)(w * 32 + rowLane)) * 512 + c * 16 + moff;
            GL2LDS16(gR,                      vsR + w * 512);
            GL2LDS16(gR + (size_t)16 * 512,   vsR + w * 512 + 256);
            GL2LDS16(gI,                      vsI + w * 512);
            GL2LDS16(gI + (size_t)16 * 512,   vsI + w * 512 + 256);
        }
        // ---- stage A slice (coalesced): embS[k*48+dj2] = embC[row + di*63]
        {
            const int dioff = di * 63;
            GL2LDS4(embC + esrc[0] + dioff, embS + 0 * 256 + w * 64);
            GL2LDS4(embC + esrc[1] + dioff, embS + 1 * 256 + w * 64);
            GL2LDS4(embC + esrc[2] + dioff, embS + 2 * 256 + w * 64);
        }
        __syncthreads();

        // ---- B-fragments (reused across 4 n)
        short8 Br[2], Bi[2];
#pragma unroll
        for (int t = 0; t < 2; ++t) {
            int rowb = w * 32 + t * 16 + col;
            Br[t] = *(const short8*)&vsR[rowb * 16 + quad * 4];
            Bi[t] = *(const short8*)&vsI[rowb * 16 + quad * 4];
        }
        // ---- A window from LDS: 12 dwords at col*48 + quad*8
        u32x4v W0 = *(const u32x4v*)&embS[col * 48 + quad * 8];
        u32x4v W1 = *(const u32x4v*)&embS[col * 48 + quad * 8 + 4];
        u32x4v W2 = *(const u32x4v*)&embS[col * 48 + quad * 8 + 8];
        unsigned W[12] = { W0.x, W0.y, W0.z, W0.w,
                           W1.x, W1.y, W1.z, W1.w,
                           W2.x, W2.y, W2.z, W2.w };

#pragma unroll
        for (int g = 0; g < 4; ++g) {
            const int o = 3 - g;                       // compile-time
            union { unsigned u[4]; short8 s; } Rr, Ri, Rin;
            Rr.u[0] = __builtin_amdgcn_perm(W[o + 1], W[o + 0], 0x05040100u);
            Rr.u[1] = __builtin_amdgcn_perm(W[o + 3], W[o + 2], 0x05040100u);
            Rr.u[2] = __builtin_amdgcn_perm(W[o + 5], W[o + 4], 0x05040100u);
            Rr.u[3] = __builtin_amdgcn_perm(W[o + 7], W[o + 6], 0x05040100u);
            Ri.u[0] = __builtin_amdgcn_perm(W[o + 1], W[o + 0], 0x07060302u);
            Ri.u[1] = __builtin_amdgcn_perm(W[o + 3], W[o + 2], 0x07060302u);
            Ri.u[2] = __builtin_amdgcn_perm(W[o + 5], W[o + 4], 0x07060302u);
            Ri.u[3] = __builtin_amdgcn_perm(W[o + 7], W[o + 6], 0x07060302u);
            Rin.u[0] = Ri.u[0] ^ 0x80008000u;
            Rin.u[1] = Ri.u[1] ^ 0x80008000u;
            Rin.u[2] = Ri.u[2] ^ 0x80008000u;
            Rin.u[3] = Ri.u[3] ^ 0x80008000u;
#pragma unroll
            for (int t = 0; t < 2; ++t) {
                accr[g][t] = __builtin_amdgcn_mfma_f32_16x16x32_bf16(Rr.s,  Br[t], accr[g][t], 0, 0, 0);
                accr[g][t] = __builtin_amdgcn_mfma_f32_16x16x32_bf16(Rin.s, Bi[t], accr[g][t], 0, 0, 0);
                acci[g][t] = __builtin_amdgcn_mfma_f32_16x16x32_bf16(Rr.s,  Bi[t], acci[g][t], 0, 0, 0);
                acci[g][t] = __builtin_amdgcn_mfma_f32_16x16x32_bf16(Ri.s,  Br[t], acci[g][t], 0, 0, 0);
            }
        }
        __syncthreads();
    }

    // ---- hoist lam_c (g-invariant)
    float2 lcv[2][4];
#pragma unroll
    for (int t = 0; t < 2; ++t) {
        int bvl = w * 32 + t * 16 + col;
        int bloc = b0 + (bvl >> 5), v = bvl & 31;
#pragma unroll
        for (int r = 0; r < 4; ++r)
            lcv[t][r] = lamc[((size_t)(bloc * KD + quad * 4 + r)) * VD + v];
    }

    // ---- epilogue (fully unrolled; g compile-time)
    const int col128 = tid & 127;
    const int hb = (tid >> 7) * 4;          // 4 heads per thread-half
    const int bl = col128 >> 5, vY = col128 & 31;
    const int bY = b0 + bl;
    float2* op2 = (float2*)out;
#pragma unroll
    for (int g = 0; g < 4; ++g) {
        __syncthreads();
#pragma unroll
        for (int t = 0; t < 2; ++t) {
            int bvl = w * 32 + t * 16 + col;
#pragma unroll
            for (int r = 0; r < 4; ++r) {
                int k = quad * 4 + r;
                lamt[k * 128 + bvl] = make_float2(accr[g][t][r] + lcv[t][r].x,
                                                  acci[g][t][r] + lcv[t][r].y);
            }
        }
        __syncthreads();
        float yr[4], yi[4];
#pragma unroll
        for (int h = 0; h < 4; ++h) { yr[h] = 0.f; yi[h] = 0.f; }
#pragma unroll
        for (int k = 0; k < 16; ++k) {
            float2 l = lamt[k * 128 + col128];
#pragma unroll
            for (int h = 0; h < 4; ++h) {
                float2 q = qsh[(bl * 128 + (hb + h) * 16 + k) * 4 + g];
                yr[h] += q.x * l.x - q.y * l.y;
                yi[h] += q.x * l.y + q.y * l.x;
            }
        }
        int n = n0 + g;
        if (cplx) {
#pragma unroll
            for (int h = 0; h < 4; ++h)
                op2[((size_t)(bY * 256 + (hb + h) * 32 + vY)) * MM + n] = make_float2(yr[h], yi[h]);
        } else {
#pragma unroll
            for (int h = 0; h < 4; ++h)
                out[((size_t)(bY * 256 + (hb + h) * 32 + vY)) * MM + n] = yr[h];
        }
    }
}

// ---------------------------------------------------------------------------
extern "C" void kernel_launch(void* const* d_in, const int* in_sizes, int n_in,
                              void* d_out, int out_size, void* d_ws, size_t ws_size,
                              hipStream_t stream)
{
    const float* x_re  = (const float*)d_in[0];
    const float* x_im  = (const float*)d_in[1];
    const float* wq_re = (const float*)d_in[2];
    const float* wq_im = (const float*)d_in[3];
    const float* wk_re = (const float*)d_in[4];
    const float* wk_im = (const float*)d_in[5];
    const float* wv_re = (const float*)d_in[6];
    const float* wv_im = (const float*)d_in[7];
    const float* qs_re = (const float*)d_in[8];
    const float* qs_im = (const float*)d_in[9];
    const float* qb_re = (const float*)d_in[10];
    const float* qb_im = (const float*)d_in[11];
    const float* vs_re = (const float*)d_in[12];
    const float* vs_im = (const float*)d_in[13];
    const float* vb_re = (const float*)d_in[14];
    const float* vb_im = (const float*)d_in[15];
    const float* emb_re = (const float*)d_in[16];
    const float* emb_im = (const float*)d_in[17];

    float* ws = (float*)d_ws;
    const size_t O_OFF  = 0;                                     // 5,767,168
    const size_t ST_OFF = O_OFF + (size_t)BB * NCH * MM * 2;     // 640
    const size_t LC_OFF = ST_OFF + 640;                          // 16,384
    const size_t EC_OFF = LC_OFF + 16384;                        // 63,504 + 64 pad
    const size_t WP_OFF = EC_OFF + 63568;                        // 98,304 (Wpk)
    const size_t VR_OFF = WP_OFF + 98304;                        // 262,144
    const size_t VI_OFF = VR_OFF + 262144;                       // 262,144

    float2*   O     = (float2*)(ws + O_OFF);
    float4*   stats = (float4*)(ws + ST_OFF);
    float2*   lamc  = (float2*)(ws + LC_OFF);
    unsigned* embC  = (unsigned*)(ws + EC_OFF);
    unsigned* Wpk   = (unsigned*)(ws + WP_OFF);
    unsigned* VbfR  = (unsigned*)(ws + VR_OFF);
    unsigned* VbfI  = (unsigned*)(ws + VI_OFF);
    float*    outp  = (float*)d_out;

    int cplx = (out_size >= 2 * BB * 256 * MM) ? 1 : 0;

    k_wprep<<<dim3(96), 256, 0, stream>>>(wq_re, wq_im, wk_re, wk_im,
                                          wv_re, wv_im, Wpk);
    k_eprep<<<dim3(249), 256, 0, stream>>>(emb_re, emb_im, embC);
    k_proj<<<dim3(32, BB), 256, 0, stream>>>(x_re, x_im, Wpk, O);
    k_bnstats<<<dim3(160), 256, 0, stream>>>(O, qs_re, qs_im, qb_re, qb_im,
                                             vs_re, vs_im, vb_re, vb_im, stats);
    k_bnapply<<<dim3(160, BB), 256, 0, stream>>>(stats, O, VbfR, VbfI);
    k_softlam<<<dim3(KD, BB), 256, 0, stream>>>(O, lamc);
    k_main<<<dim3(256, 4), 256, 0, stream>>>(O, embC, VbfR, VbfI, lamc, outp, cplx);
}

// Round 8
// 282.920 us; speedup vs baseline: 1.2534x; 1.0052x over previous
//
#include <hip/hip_runtime.h>
#include <math.h>

// Problem constants
#define DIMC 256   // input channels
#define NCH  176   // 128 q + 16 k + 32 v output channels
#define MM   1024  // N2 spatial
#define BB   16    // batch
#define KD   16    // DIM_K
#define HH   8     // heads
#define VD   32    // DIM_V
#define EPSV 1e-5
#define OPAD 192   // padded output channels for MFMA proj (12 o-tiles)

typedef short short8 __attribute__((ext_vector_type(8)));
typedef float f32x4  __attribute__((ext_vector_type(4)));
typedef unsigned u32x4v __attribute__((ext_vector_type(4)));

union frag8 { unsigned u[4]; short8 s; u32x4v v; };

__device__ __forceinline__ unsigned bf16rne(float f) {
    unsigned u = __float_as_uint(f);
    unsigned r = u + 0x7FFFu + ((u >> 16) & 1u);
    return r >> 16;
}
__device__ __forceinline__ float bf16tof(unsigned h) {
    return __uint_as_float(h << 16);
}

#define GL2LDS16(g, l) __builtin_amdgcn_global_load_lds( \
    (const __attribute__((address_space(1))) unsigned*)(g), \
    (__attribute__((address_space(3))) unsigned*)(l), 16, 0, 0)
#define GL2LDS4(g, l) __builtin_amdgcn_global_load_lds( \
    (const __attribute__((address_space(1))) unsigned*)(g), \
    (__attribute__((address_space(3))) unsigned*)(l), 4, 0, 0)

// ---------------------------------------------------------------------------
// k_wprep: pack W (q|k|v concat, padded to 192 rows) into 4 planes of
// [192][128] u32 (re_hi / im_hi / re_lo / im_lo, split-bf16).  (unchanged)
// ---------------------------------------------------------------------------
__global__ __launch_bounds__(256) void k_wprep(
    const float* __restrict__ wq_re, const float* __restrict__ wq_im,
    const float* __restrict__ wk_re, const float* __restrict__ wk_im,
    const float* __restrict__ wv_re, const float* __restrict__ wv_im,
    unsigned* __restrict__ Wpk)
{
    int idx = blockIdx.x * 256 + threadIdx.x;   // 0..24575
    if (idx >= OPAD * 128) return;
    int o = idx >> 7, j = idx & 127;
    int c0 = 2 * j;
    float r0 = 0.f, r1 = 0.f, i0 = 0.f, i1 = 0.f;
    if (o < 128) {
        r0 = wq_re[o * DIMC + c0]; r1 = wq_re[o * DIMC + c0 + 1];
        i0 = wq_im[o * DIMC + c0]; i1 = wq_im[o * DIMC + c0 + 1];
    } else if (o < 144) {
        int oo = o - 128;
        r0 = wk_re[oo * DIMC + c0]; r1 = wk_re[oo * DIMC + c0 + 1];
        i0 = wk_im[oo * DIMC + c0]; i1 = wk_im[oo * DIMC + c0 + 1];
    } else if (o < 176) {
        int oo = o - 144;
        r0 = wv_re[oo * DIMC + c0]; r1 = wv_re[oo * DIMC + c0 + 1];
        i0 = wv_im[oo * DIMC + c0]; i1 = wv_im[oo * DIMC + c0 + 1];
    }
    unsigned rh0 = bf16rne(r0), rh1 = bf16rne(r1);
    unsigned ih0 = bf16rne(i0), ih1 = bf16rne(i1);
    float rl0 = r0 - bf16tof(rh0), rl1 = r1 - bf16tof(rh1);
    float il0 = i0 - bf16tof(ih0), il1 = i1 - bf16tof(ih1);
    Wpk[0 * OPAD * 128 + idx] = rh0 | (rh1 << 16);
    Wpk[1 * OPAD * 128 + idx] = ih0 | (ih1 << 16);
    Wpk[2 * OPAD * 128 + idx] = bf16rne(rl0) | (bf16rne(rl1) << 16);
    Wpk[3 * OPAD * 128 + idx] = bf16rne(il0) | (bf16rne(il1) << 16);
}

// ---------------------------------------------------------------------------
// k_proj (MFMA, split-bf16, kk-loop not unrolled).  (unchanged)
// ---------------------------------------------------------------------------
__global__ __launch_bounds__(256, 2) void k_proj(
    const float* __restrict__ x_re, const float* __restrict__ x_im,
    const unsigned* __restrict__ Wpk,
    float2* __restrict__ O)
{
    const int m0  = blockIdx.x * 32;
    const int b   = blockIdx.y;
    const int tid = threadIdx.x;
    const int w    = tid >> 6;
    const int lane = tid & 63;
    const int quad = lane >> 4;
    const int col  = lane & 15;
    const int mt = w & 1, og = w >> 1;

    __shared__ __align__(16) unsigned Wsh[4 * OPAD * 16];  // 48 KB
    __shared__ __align__(16) unsigned Xsh[4 * 32 * 20];    // 10 KB

    f32x4 accR[6], accI[6];
#pragma unroll
    for (int t = 0; t < 6; ++t) {
        accR[t] = (f32x4){0.f, 0.f, 0.f, 0.f};
        accI[t] = (f32x4){0.f, 0.f, 0.f, 0.f};
    }

    const int ms = tid & 31;
    const int cps = tid >> 5;

#pragma unroll 1
    for (int kk = 0; kk < 8; ++kk) {
#pragma unroll
        for (int p = 0; p < 12; ++p) {
            int idx = p * 256 + tid;
            int plane = idx / 768;
            int rem = idx - plane * 768;
            int row = rem >> 2, seg = rem & 3;
            u32x4v d = *(const u32x4v*)&Wpk[(size_t)plane * (OPAD * 128) + row * 128 + kk * 16 + seg * 4];
            *(u32x4v*)&Wsh[(plane * OPAD + row) * 16 + seg * 4] = d;
        }
#pragma unroll
        for (int p = 0; p < 2; ++p) {
            int cp = cps + p * 8;
            int c  = kk * 32 + cp * 2;
            size_t base = ((size_t)(b * DIMC + c)) * MM + m0 + ms;
            float r0 = x_re[base],      i0 = x_im[base];
            float r1 = x_re[base + MM], i1 = x_im[base + MM];
            unsigned rh0 = bf16rne(r0), rh1 = bf16rne(r1);
            unsigned ih0 = bf16rne(i0), ih1 = bf16rne(i1);
            float rl0 = r0 - bf16tof(rh0), rl1 = r1 - bf16tof(rh1);
            float il0 = i0 - bf16tof(ih0), il1 = i1 - bf16tof(ih1);
            Xsh[0 * 640 + ms * 20 + cp] = rh0 | (rh1 << 16);
            Xsh[1 * 640 + ms * 20 + cp] = ih0 | (ih1 << 16);
            Xsh[2 * 640 + ms * 20 + cp] = bf16rne(rl0) | (bf16rne(rl1) << 16);
            Xsh[3 * 640 + ms * 20 + cp] = bf16rne(il0) | (bf16rne(il1) << 16);
        }
        __syncthreads();

        int mrow = mt * 16 + col;
        short8 Xrh = *(const short8*)&Xsh[0 * 640 + mrow * 20 + quad * 4];
        short8 Xih = *(const short8*)&Xsh[1 * 640 + mrow * 20 + quad * 4];
        short8 Xrl = *(const short8*)&Xsh[2 * 640 + mrow * 20 + quad * 4];
        short8 Xil = *(const short8*)&Xsh[3 * 640 + mrow * 20 + quad * 4];

#pragma unroll
        for (int ot = 0; ot < 6; ++ot) {
            int orow = (og * 6 + ot) * 16 + col;
            frag8 Arh, Aih, Arl, Ail, Anh, Anl;
            Arh.s = *(const short8*)&Wsh[(0 * OPAD + orow) * 16 + quad * 4];
            Aih.s = *(const short8*)&Wsh[(1 * OPAD + orow) * 16 + quad * 4];
            Arl.s = *(const short8*)&Wsh[(2 * OPAD + orow) * 16 + quad * 4];
            Ail.s = *(const short8*)&Wsh[(3 * OPAD + orow) * 16 + quad * 4];
#pragma unroll
            for (int i = 0; i < 4; ++i) {
                Anh.u[i] = Aih.u[i] ^ 0x80008000u;
                Anl.u[i] = Ail.u[i] ^ 0x80008000u;
            }
            accR[ot] = __builtin_amdgcn_mfma_f32_16x16x32_bf16(Arh.s, Xrh, accR[ot], 0, 0, 0);
            accR[ot] = __builtin_amdgcn_mfma_f32_16x16x32_bf16(Anh.s, Xih, accR[ot], 0, 0, 0);
            accR[ot] = __builtin_amdgcn_mfma_f32_16x16x32_bf16(Arh.s, Xrl, accR[ot], 0, 0, 0);
            accR[ot] = __builtin_amdgcn_mfma_f32_16x16x32_bf16(Anh.s, Xil, accR[ot], 0, 0, 0);
            accR[ot] = __builtin_amdgcn_mfma_f32_16x16x32_bf16(Arl.s, Xrh, accR[ot], 0, 0, 0);
            accR[ot] = __builtin_amdgcn_mfma_f32_16x16x32_bf16(Anl.s, Xih, accR[ot], 0, 0, 0);
            accI[ot] = __builtin_amdgcn_mfma_f32_16x16x32_bf16(Arh.s, Xih, accI[ot], 0, 0, 0);
            accI[ot] = __builtin_amdgcn_mfma_f32_16x16x32_bf16(Aih.s, Xrh, accI[ot], 0, 0, 0);
            accI[ot] = __builtin_amdgcn_mfma_f32_16x16x32_bf16(Arh.s, Xil, accI[ot], 0, 0, 0);
            accI[ot] = __builtin_amdgcn_mfma_f32_16x16x32_bf16(Aih.s, Xrl, accI[ot], 0, 0, 0);
            accI[ot] = __builtin_amdgcn_mfma_f32_16x16x32_bf16(Arl.s, Xih, accI[ot], 0, 0, 0);
            accI[ot] = __builtin_amdgcn_mfma_f32_16x16x32_bf16(Ail.s, Xrh, accI[ot], 0, 0, 0);
        }
        __syncthreads();
    }

#pragma unroll
    for (int ot = 0; ot < 6; ++ot) {
        int gto = og * 6 + ot;
        if (gto >= 11) continue;
#pragma unroll
        for (int r = 0; r < 4; ++r) {
            int o = gto * 16 + quad * 4 + r;
            O[((size_t)(b * NCH + o)) * MM + m0 + mt * 16 + col] =
                make_float2(accR[ot][r], accI[ot][r]);
        }
    }
}

// ---------------------------------------------------------------------------
// K2: complex BN stats (double accumulation)  (unchanged)
// ---------------------------------------------------------------------------
__global__ __launch_bounds__(256) void k_bnstats(
    const float2* __restrict__ O,
    const float* __restrict__ qs_re, const float* __restrict__ qs_im,
    const float* __restrict__ qb_re, const float* __restrict__ qb_im,
    const float* __restrict__ vs_re, const float* __restrict__ vs_im,
    const float* __restrict__ vb_re, const float* __restrict__ vb_im,
    float4* __restrict__ stats)
{
    const int ch  = blockIdx.x;
    const int o   = (ch < 128) ? ch : (144 + ch - 128);
    const int tid = threadIdx.x;

    double sr = 0, si = 0, sq = 0, sri = 0;
    for (int idx = tid; idx < BB * MM; idx += 256) {
        int b = idx >> 10, m = idx & 1023;
        float2 val = O[((size_t)(b * NCH + o)) * MM + m];
        double r = val.x, ii = val.y;
        sr += r; si += ii; sq += r * r - ii * ii; sri += r * ii;
    }
    __shared__ double red[4][256];
    red[0][tid] = sr; red[1][tid] = si; red[2][tid] = sq; red[3][tid] = sri;
    __syncthreads();
    for (int s = 128; s > 0; s >>= 1) {
        if (tid < s) {
            red[0][tid] += red[0][tid + s]; red[1][tid] += red[1][tid + s];
            red[2][tid] += red[2][tid + s]; red[3][tid] += red[3][tid + s];
        }
        __syncthreads();
    }
    if (tid == 0) {
        const double inv = 1.0 / (double)(BB * MM);
        double mr = red[0][0] * inv, mi = red[1][0] * inv;
        double vr = red[2][0] * inv - (mr * mr - mi * mi) + EPSV;
        double vi = 2.0 * (red[3][0] * inv - mr * mi);
        double rad = sqrt(vr * vr + vi * vi);
        double wr  = sqrt(fmax(0.5 * (rad + vr), 0.0));
        double wi  = sqrt(fmax(0.5 * (rad - vr), 0.0));
        if (vi < 0) wi = -wi;
        double den = wr * wr + wi * wi;
        double ivr = wr / den, ivi = -wi / den;
        double scr, sci, shr, shi;
        if (ch < 128) { scr = qs_re[ch]; sci = qs_im[ch]; shr = qb_re[ch]; shi = qb_im[ch]; }
        else { int i2 = ch - 128; scr = vs_re[i2]; sci = vs_im[i2]; shr = vb_re[i2]; shi = vb_im[i2]; }
        double Ar = scr * ivr - sci * ivi;
        double Ai = scr * ivi + sci * ivr;
        double Br = shr - (Ar * mr - Ai * mi);
        double Bi = shi - (Ar * mi + Ai * mr);
        stats[ch] = make_float4((float)Ar, (float)Ai, (float)Br, (float)Bi);
    }
}

// ---------------------------------------------------------------------------
// K3a: apply BN affine in place; v channels emit bf16 planes in CHUNK-MAJOR
// swizzled layout VbfR/I[c(32)][bv(512)][16 dwords] — per-chunk slice for a
// bv-quarter is a contiguous 8 KB region (linear GL2LDS staging in k_main),
// and the 4-dword unit index is XOR-swizzled by (bv&3) for conflict-free
// ds_read_b128.
// ---------------------------------------------------------------------------
__global__ __launch_bounds__(256) void k_bnapply(
    const float4* __restrict__ stats, float2* __restrict__ O,
    unsigned* __restrict__ VR, unsigned* __restrict__ VI)
{
    int ch = blockIdx.x, b = blockIdx.y;
    int o  = (ch < 128) ? ch : (144 + ch - 128);
    float4 s = stats[ch];
    float2* row = O + ((size_t)(b * NCH + o)) * MM;
    int tid = threadIdx.x;
    for (int mm = tid; mm < 512; mm += 256) {
        float4 two = *(float4*)&row[2 * mm];
        float nr0 = s.x * two.x - s.y * two.y + s.z;
        float ni0 = s.x * two.y + s.y * two.x + s.w;
        float nr1 = s.x * two.z - s.y * two.w + s.z;
        float ni1 = s.x * two.w + s.y * two.z + s.w;
        *(float4*)&row[2 * mm] = make_float4(nr0, ni0, nr1, ni1);
        if (ch >= 128) {
            int bv = b * VD + (ch - 128);
            int cC = mm >> 4, off = mm & 15;
            int u = off >> 2, oo = off & 3;
            int sl = (((u ^ (bv & 3)) << 2) | oo);
            size_t idx = ((size_t)cC * 512 + bv) * 16 + sl;
            VR[idx] = bf16rne(nr0) | (bf16rne(nr1) << 16);
            VI[idx] = bf16rne(ni0) | (bf16rne(ni1) << 16);
        }
    }
}

// ---------------------------------------------------------------------------
// k_softlam: softmax over m of |k| fused with content lambda  (unchanged)
// ---------------------------------------------------------------------------
__global__ __launch_bounds__(256) void k_softlam(
    const float2* __restrict__ O, float2* __restrict__ lamc)
{
    int kc = blockIdx.x, b = blockIdx.y;
    const float2* row = O + ((size_t)(b * NCH + 128 + kc)) * MM;
    int tid = threadIdx.x;
    __shared__ float red[256];
    __shared__ float skl[1024];

    float mag[4]; float mx = -1e30f;
#pragma unroll
    for (int j = 0; j < 4; ++j) {
        float2 v = row[tid + j * 256];
        mag[j] = sqrtf(v.x * v.x + v.y * v.y);
        mx = fmaxf(mx, mag[j]);
    }
    red[tid] = mx; __syncthreads();
    for (int s = 128; s > 0; s >>= 1) { if (tid < s) red[tid] = fmaxf(red[tid], red[tid + s]); __syncthreads(); }
    mx = red[0]; __syncthreads();
    float e[4]; float sum = 0.f;
#pragma unroll
    for (int j = 0; j < 4; ++j) { e[j] = expf(mag[j] - mx); sum += e[j]; }
    red[tid] = sum; __syncthreads();
    for (int s = 128; s > 0; s >>= 1) { if (tid < s) red[tid] += red[tid + s]; __syncthreads(); }
    float inv = 1.f / red[0];
#pragma unroll
    for (int j = 0; j < 4; ++j) skl[tid + j * 256] = e[j] * inv;
    __syncthreads();

    int v = tid >> 3, s8 = tid & 7;
    const float2* vrow = O + ((size_t)(b * NCH + 144 + v)) * MM;
    float ar = 0.f, ai = 0.f;
    for (int i = 0; i < 128; ++i) {
        int m = s8 * 128 + i;
        float wgt = skl[m]; float2 vv = vrow[m];
        ar += wgt * vv.x; ai += wgt * vv.y;
    }
    __shared__ float2 part[32][8];
    part[v][s8] = make_float2(ar, ai);
    __syncthreads();
    if (tid < 32) {
        float2 t = part[tid][0];
#pragma unroll
        for (int j = 1; j < 8; ++j) { t.x += part[tid][j].x; t.y += part[tid][j].y; }
        lamc[((size_t)(b * KD + kc)) * VD + tid] = t;
    }
}

// ---------------------------------------------------------------------------
// k_eprepD — expand emb into embD[win(8)][di(63)][k(16)][48 slots] u32
// (bf16 re | im<<16). win = nj0>>2 selects the 48-dj window djBase=28-nj0.
// The 4-dword unit index within each k-row is XOR-swizzled by
// p(k) = ((k>>1)&1)*2 + ((k>>2)&1) for conflict-light ds_read_b128.
// Out-of-range dj (>62) padded with zero (never consumed).
// ---------------------------------------------------------------------------
__global__ __launch_bounds__(256) void k_eprepD(
    const float* __restrict__ er, const float* __restrict__ ei,
    unsigned* __restrict__ embD)
{
    int idx = blockIdx.x * 256 + threadIdx.x;     // 0 .. 8*63*768-1
    if (idx >= 8 * 63 * 768) return;
    int s   = idx % 48;
    int k   = (idx / 48) % 16;
    int di  = (idx / 768) % 63;
    int win = idx / (768 * 63);
    int u_s = s >> 2, o = s & 3;
    int p   = (((k >> 1) & 1) << 1) | ((k >> 2) & 1);
    int dj2 = ((u_s ^ p) << 2) | o;               // logical dj offset
    int dj  = 28 - win * 4 + dj2;
    unsigned val = 0;
    if (dj <= 62) {
        int e = (di * 63 + dj) * 16 + k;
        val = bf16rne(er[e]) | (bf16rne(ei[e]) << 16);
    }
    embD[idx] = val;
}

// ---------------------------------------------------------------------------
// k_main (R8): double-buffered staging, 1 barrier/chunk.
// R8 changes vs R7:
//  - LDS double-buffer for V+emb: prefetch chunk c+1 issued right after the
//    barrier that publishes chunk c; its vmcnt drain happens at the *next*
//    barrier, overlapped with the full compute phase. R7 was single-buffered
//    (2 barriers/chunk, delivery + compute strictly serial — all pipes <23%).
//  - V staged from chunk-major layout: pure linear 8 KB copy, full-line
//    coalesced (R7 staged 64 B half-lines from 16 scattered rows/instr).
//  - emb staged from pre-expanded embD: one contiguous 3 KB linear copy.
//  - XOR swizzle baked into both tables -> B-frag / A-window ds_read_b128
//    conflicts drop 8-way -> <=2-way.
// ---------------------------------------------------------------------------
__global__ __launch_bounds__(256, 2) void k_main(
    const float2* __restrict__ O,
    const unsigned* __restrict__ embD,
    const unsigned* __restrict__ VbfR,
    const unsigned* __restrict__ VbfI,
    const float2* __restrict__ lamc,
    float* __restrict__ out, int cplx)
{
    const int tid  = threadIdx.x;
    const int w    = tid >> 6;
    const int lane = tid & 63;
    const int quad = lane >> 4;
    const int col  = lane & 15;

    const int n0  = blockIdx.x * 4;
    const int bvq = blockIdx.y;        // 0..3, 128 bv rows each
    const int b0  = bvq * 4;
    const int ni  = n0 >> 5;
    const int nj0 = n0 & 31;
    const int win = nj0 >> 2;

    // dbuf: per buffer vsR 2048 + vsI 2048 + embS 768 = 4864 dwords (19 KB)
    __shared__ __align__(16) unsigned shraw[2 * 4864];   // 38 KB
    __shared__ __align__(16) float2 qsh[2048];           // 16 KB

    // stage q tile (BN already applied in place)
#pragma unroll
    for (int it = 0; it < 8; ++it) {
        int idx = it * 256 + tid;
        int g = idx & 3, ch = (idx >> 2) & 127, bl = idx >> 9;
        qsh[idx] = O[((size_t)((b0 + bl) * NCH + ch)) * MM + n0 + g];
    }

    f32x4 accr[4][2], acci[4][2];
#pragma unroll
    for (int g = 0; g < 4; ++g)
#pragma unroll
        for (int t = 0; t < 2; ++t) {
            accr[g][t] = (f32x4){0.f, 0.f, 0.f, 0.f};
            acci[g][t] = (f32x4){0.f, 0.f, 0.f, 0.f};
        }

    // per-lane staging source pointers (chunk-invariant parts)
    const unsigned* vR0 = VbfR + (size_t)bvq * 2048 + w * 512 + lane * 4;
    const unsigned* vI0 = VbfI + (size_t)bvq * 2048 + w * 512 + lane * 4;
    const unsigned* eD0 = embD + (size_t)win * (63 * 768) + w * 64 + lane;

    // reader address constants
    const int p     = (((col >> 1) & 1) << 1) | ((col >> 2) & 1);
    const int aBase = col * 48;
    const int a0 = aBase + (((2 * quad)     ^ p) << 2);
    const int a1 = aBase + (((2 * quad + 1) ^ p) << 2);
    const int a2 = aBase + (((2 * quad + 2) ^ p) << 2);
    const int bswz  = (quad ^ (col & 3)) << 2;
    const int rowb0 = (w * 32 + col) * 16 + bswz;
    const int rowb1 = (w * 32 + 16 + col) * 16 + bswz;

    // prefetch chunk 0 into buffer 0
    {
        unsigned* vr = shraw;
        unsigned* vi = shraw + 2048;
        unsigned* es = shraw + 4096;
        GL2LDS16(vR0,       vr + w * 512);
        GL2LDS16(vR0 + 256, vr + w * 512 + 256);
        GL2LDS16(vI0,       vi + w * 512);
        GL2LDS16(vI0 + 256, vi + w * 512 + 256);
        const unsigned* gE = eD0 + (size_t)(31 - ni) * 768;   // di(c=0)
        GL2LDS4(gE,       es + w * 64);
        GL2LDS4(gE + 256, es + 256 + w * 64);
        GL2LDS4(gE + 512, es + 512 + w * 64);
    }

#pragma unroll 1
    for (int c = 0; c < 32; ++c) {
        __syncthreads();   // drains prefetch of chunk c; buf[c&1] published

        if (c + 1 < 32) {  // prefetch chunk c+1 into other buffer
            unsigned* vr = shraw + ((c + 1) & 1) * 4864;
            unsigned* vi = vr + 2048;
            unsigned* es = vr + 4096;
            const unsigned* gR = vR0 + (size_t)(c + 1) * 8192;
            const unsigned* gI = vI0 + (size_t)(c + 1) * 8192;
            GL2LDS16(gR,       vr + w * 512);
            GL2LDS16(gR + 256, vr + w * 512 + 256);
            GL2LDS16(gI,       vi + w * 512);
            GL2LDS16(gI + 256, vi + w * 512 + 256);
            const unsigned* gE = eD0 + (size_t)(c + 1 - ni + 31) * 768;
            GL2LDS4(gE,       es + w * 64);
            GL2LDS4(gE + 256, es + 256 + w * 64);
            GL2LDS4(gE + 512, es + 512 + w * 64);
        }

        const unsigned* vr = shraw + (c & 1) * 4864;
        const unsigned* vi = vr + 2048;
        const unsigned* es = vr + 4096;

        // B-fragments (swizzled rows)
        short8 Br0 = *(const short8*)&vr[rowb0];
        short8 Br1 = *(const short8*)&vr[rowb1];
        short8 Bi0 = *(const short8*)&vi[rowb0];
        short8 Bi1 = *(const short8*)&vi[rowb1];

        // A window: 12 logical dwords (units 2q, 2q+1, 2q+2, de-swizzled)
        u32x4v W0 = *(const u32x4v*)&es[a0];
        u32x4v W1 = *(const u32x4v*)&es[a1];
        u32x4v W2 = *(const u32x4v*)&es[a2];
        unsigned W[12] = { W0.x, W0.y, W0.z, W0.w,
                           W1.x, W1.y, W1.z, W1.w,
                           W2.x, W2.y, W2.z, W2.w };

#pragma unroll
        for (int g = 0; g < 4; ++g) {
            const int o = 3 - g;                       // compile-time
            union { unsigned u[4]; short8 s; } Rr, Ri, Rin;
            Rr.u[0] = __builtin_amdgcn_perm(W[o + 1], W[o + 0], 0x05040100u);
            Rr.u[1] = __builtin_amdgcn_perm(W[o + 3], W[o + 2], 0x05040100u);
            Rr.u[2] = __builtin_amdgcn_perm(W[o + 5], W[o + 4], 0x05040100u);
            Rr.u[3] = __builtin_amdgcn_perm(W[o + 7], W[o + 6], 0x05040100u);
            Ri.u[0] = __builtin_amdgcn_perm(W[o + 1], W[o + 0], 0x07060302u);
            Ri.u[1] = __builtin_amdgcn_perm(W[o + 3], W[o + 2], 0x07060302u);
            Ri.u[2] = __builtin_amdgcn_perm(W[o + 5], W[o + 4], 0x07060302u);
            Ri.u[3] = __builtin_amdgcn_perm(W[o + 7], W[o + 6], 0x07060302u);
            Rin.u[0] = Ri.u[0] ^ 0x80008000u;
            Rin.u[1] = Ri.u[1] ^ 0x80008000u;
            Rin.u[2] = Ri.u[2] ^ 0x80008000u;
            Rin.u[3] = Ri.u[3] ^ 0x80008000u;
            accr[g][0] = __builtin_amdgcn_mfma_f32_16x16x32_bf16(Rr.s,  Br0, accr[g][0], 0, 0, 0);
            accr[g][0] = __builtin_amdgcn_mfma_f32_16x16x32_bf16(Rin.s, Bi0, accr[g][0], 0, 0, 0);
            acci[g][0] = __builtin_amdgcn_mfma_f32_16x16x32_bf16(Rr.s,  Bi0, acci[g][0], 0, 0, 0);
            acci[g][0] = __builtin_amdgcn_mfma_f32_16x16x32_bf16(Ri.s,  Br0, acci[g][0], 0, 0, 0);
            accr[g][1] = __builtin_amdgcn_mfma_f32_16x16x32_bf16(Rr.s,  Br1, accr[g][1], 0, 0, 0);
            accr[g][1] = __builtin_amdgcn_mfma_f32_16x16x32_bf16(Rin.s, Bi1, accr[g][1], 0, 0, 0);
            acci[g][1] = __builtin_amdgcn_mfma_f32_16x16x32_bf16(Rr.s,  Bi1, acci[g][1], 0, 0, 0);
            acci[g][1] = __builtin_amdgcn_mfma_f32_16x16x32_bf16(Ri.s,  Br1, acci[g][1], 0, 0, 0);
        }
    }

    // ---- hoist lam_c (g-invariant)
    float2 lcv[2][4];
#pragma unroll
    for (int t = 0; t < 2; ++t) {
        int bvl = w * 32 + t * 16 + col;
        int bloc = b0 + (bvl >> 5), v = bvl & 31;
#pragma unroll
        for (int r = 0; r < 4; ++r)
            lcv[t][r] = lamc[((size_t)(bloc * KD + quad * 4 + r)) * VD + v];
    }

    // ---- epilogue (fully unrolled; g compile-time); lamt reuses buffer 0
    float2* lamt = (float2*)shraw;                    // [16k][128bv]
    const int col128 = tid & 127;
    const int hb = (tid >> 7) * 4;
    const int bl = col128 >> 5, vY = col128 & 31;
    const int bY = b0 + bl;
    float2* op2 = (float2*)out;
#pragma unroll
    for (int g = 0; g < 4; ++g) {
        __syncthreads();
#pragma unroll
        for (int t = 0; t < 2; ++t) {
            int bvl = w * 32 + t * 16 + col;
#pragma unroll
            for (int r = 0; r < 4; ++r) {
                int k = quad * 4 + r;
                lamt[k * 128 + bvl] = make_float2(accr[g][t][r] + lcv[t][r].x,
                                                  acci[g][t][r] + lcv[t][r].y);
            }
        }
        __syncthreads();
        float yr[4], yi[4];
#pragma unroll
        for (int h = 0; h < 4; ++h) { yr[h] = 0.f; yi[h] = 0.f; }
#pragma unroll
        for (int k = 0; k < 16; ++k) {
            float2 l = lamt[k * 128 + col128];
#pragma unroll
            for (int h = 0; h < 4; ++h) {
                float2 q = qsh[(bl * 128 + (hb + h) * 16 + k) * 4 + g];
                yr[h] += q.x * l.x - q.y * l.y;
                yi[h] += q.x * l.y + q.y * l.x;
            }
        }
        int n = n0 + g;
        if (cplx) {
#pragma unroll
            for (int h = 0; h < 4; ++h)
                op2[((size_t)(bY * 256 + (hb + h) * 32 + vY)) * MM + n] = make_float2(yr[h], yi[h]);
        } else {
#pragma unroll
            for (int h = 0; h < 4; ++h)
                out[((size_t)(bY * 256 + (hb + h) * 32 + vY)) * MM + n] = yr[h];
        }
    }
}

// ---------------------------------------------------------------------------
extern "C" void kernel_launch(void* const* d_in, const int* in_sizes, int n_in,
                              void* d_out, int out_size, void* d_ws, size_t ws_size,
                              hipStream_t stream)
{
    const float* x_re  = (const float*)d_in[0];
    const float* x_im  = (const float*)d_in[1];
    const float* wq_re = (const float*)d_in[2];
    const float* wq_im = (const float*)d_in[3];
    const float* wk_re = (const float*)d_in[4];
    const float* wk_im = (const float*)d_in[5];
    const float* wv_re = (const float*)d_in[6];
    const float* wv_im = (const float*)d_in[7];
    const float* qs_re = (const float*)d_in[8];
    const float* qs_im = (const float*)d_in[9];
    const float* qb_re = (const float*)d_in[10];
    const float* qb_im = (const float*)d_in[11];
    const float* vs_re = (const float*)d_in[12];
    const float* vs_im = (const float*)d_in[13];
    const float* vb_re = (const float*)d_in[14];
    const float* vb_im = (const float*)d_in[15];
    const float* emb_re = (const float*)d_in[16];
    const float* emb_im = (const float*)d_in[17];

    float* ws = (float*)d_ws;
    const size_t O_OFF  = 0;                                     // 5,767,168
    const size_t ST_OFF = O_OFF + (size_t)BB * NCH * MM * 2;     // 640
    const size_t LC_OFF = ST_OFF + 640;                          // 16,384
    const size_t WP_OFF = LC_OFF + 16384;                        // 98,304 (Wpk)
    const size_t VR_OFF = WP_OFF + 98304;                        // 262,144
    const size_t VI_OFF = VR_OFF + 262144;                       // 262,144
    const size_t ED_OFF = VI_OFF + 262144;                       // 387,072 (embD)

    float2*   O     = (float2*)(ws + O_OFF);
    float4*   stats = (float4*)(ws + ST_OFF);
    float2*   lamc  = (float2*)(ws + LC_OFF);
    unsigned* Wpk   = (unsigned*)(ws + WP_OFF);
    unsigned* VbfR  = (unsigned*)(ws + VR_OFF);
    unsigned* VbfI  = (unsigned*)(ws + VI_OFF);
    unsigned* embD  = (unsigned*)(ws + ED_OFF);
    float*    outp  = (float*)d_out;

    int cplx = (out_size >= 2 * BB * 256 * MM) ? 1 : 0;

    k_wprep<<<dim3(96), 256, 0, stream>>>(wq_re, wq_im, wk_re, wk_im,
                                          wv_re, wv_im, Wpk);
    k_eprepD<<<dim3(1512), 256, 0, stream>>>(emb_re, emb_im, embD);
    k_proj<<<dim3(32, BB), 256, 0, stream>>>(x_re, x_im, Wpk, O);
    k_bnstats<<<dim3(160), 256, 0, stream>>>(O, qs_re, qs_im, qb_re, qb_im,
                                             vs_re, vs_im, vb_re, vb_im, stats);
    k_bnapply<<<dim3(160, BB), 256, 0, stream>>>(stats, O, VbfR, VbfI);
    k_softlam<<<dim3(KD, BB), 256, 0, stream>>>(O, lamc);
    k_main<<<dim3(256, 4), 256, 0, stream>>>(O, embD, VbfR, VbfI, lamc, outp, cplx);
}